// Round 13
// baseline (110.134 us; speedup 1.0000x reference)
//
#include <hip/hip_runtime.h>
#include <cstdint>
#include <cstddef>

// Poincare-ball (hyperbolic) attention block. B=2, S=2048, D=256, H=8, dh=32, c=1.
//
// Round 13 (attn_mfma only, vs round 12):
//  - Explicit 2-deep software pipeline: tile i+1's 4 kfrag loads + 4 Vsum
//    scalars issue BEFORE tile i's divergent compute region (hipcc cannot
//    hoist vector loads across the divergent if/else whose else-side writes
//    LDS). A/B named register sets, fully unrolled -> no dynamic indexing.

#define ALPHA 0.17677669529663687f   // 1/sqrt(32)
#define EMIN  -3.1129694f            // -ALPHA * log2((2-1e-5)/1e-5)  (clip)
#define CHI   1.95e-5f               // conservative 1-(1-1e-5)^2
#define NEG_INV_2CHI -25641.026f     // -1/(2*CHI)

typedef __bf16 bf16x8 __attribute__((ext_vector_type(8)));
typedef float  f32x4  __attribute__((ext_vector_type(4)));

__device__ __forceinline__ float fast_log2(float x) { return __builtin_amdgcn_logf(x); }
__device__ __forceinline__ float fast_exp2(float x) { return __builtin_amdgcn_exp2f(x); }

// ---------------------------------------------------------------------------
// K1: fused {Wcomb = Wfc@Wo (blocks 0-15)} {bcomb = Wfc@bo+bfc (16-31)}
//     {fp32->bf16 h/l splits of x, Wq, Wk, Wv (32-639)}.
__global__ __launch_bounds__(256)
void k1_misc(const float* __restrict__ x,   const float* __restrict__ Wq,
             const float* __restrict__ Wk,  const float* __restrict__ Wv,
             const float* __restrict__ Wfc, const float* __restrict__ Wo,
             const float* __restrict__ bo,  const float* __restrict__ bfc,
             __bf16* __restrict__ xh, __bf16* __restrict__ xl,
             __bf16* __restrict__ Ws, __bf16* __restrict__ Wch,
             __bf16* __restrict__ Wcl, float* __restrict__ bcomb) {
  __shared__ float sh[2 * 32 * 68];
  const int bx = blockIdx.x, tid = threadIdx.x;
  if (bx < 16) {
    // ---- Wcomb = Wfc @ Wo (NN, 256^3), fp32, bf16 h/l out ----
    float (*AsT)[68] = (float(*)[68])sh;
    float (*Bs)[68]  = (float(*)[68])(sh + 32 * 68);
    const int ty = tid >> 4, tx = tid & 15;
    const int m0 = (bx >> 2) * 64, n0 = (bx & 3) * 64;
    float acc[4][4] = {};
    for (int k0 = 0; k0 < 256; k0 += 32) {
#pragma unroll
      for (int jj = 0; jj < 2; ++jj) {
        int j = tid * 2 + jj;
        {
          int r = j >> 3, c4 = (j & 7) << 2;
          float4 av = *(const float4*)&Wfc[(size_t)(m0 + r) * 256 + k0 + c4];
          AsT[c4 + 0][r] = av.x; AsT[c4 + 1][r] = av.y;
          AsT[c4 + 2][r] = av.z; AsT[c4 + 3][r] = av.w;
        }
        {
          int r = j >> 4, c4 = (j & 15) << 2;
          *(float4*)&Bs[r][c4] = *(const float4*)&Wo[(size_t)(k0 + r) * 256 + n0 + c4];
        }
      }
      __syncthreads();
#pragma unroll
      for (int kk = 0; kk < 32; ++kk) {
        float4 a = *(const float4*)&AsT[kk][ty * 4];
        float4 b = *(const float4*)&Bs[kk][tx * 4];
        float av[4] = {a.x, a.y, a.z, a.w};
        float bv[4] = {b.x, b.y, b.z, b.w};
#pragma unroll
        for (int i = 0; i < 4; ++i)
#pragma unroll
          for (int j2 = 0; j2 < 4; ++j2)
            acc[i][j2] = fmaf(av[i], bv[j2], acc[i][j2]);
      }
      __syncthreads();
    }
#pragma unroll
    for (int i = 0; i < 4; ++i) {
      union { __bf16 h[4]; uint2 u; } ph, pl;
#pragma unroll
      for (int j = 0; j < 4; ++j) {
        __bf16 hb = (__bf16)acc[i][j];
        ph.h[j] = hb;
        pl.h[j] = (__bf16)(acc[i][j] - (float)hb);
      }
      size_t off = (size_t)(m0 + ty * 4 + i) * 256 + n0 + tx * 4;
      *(uint2*)(Wch + off) = ph.u;
      *(uint2*)(Wcl + off) = pl.u;
    }
  } else if (bx < 32) {
    // ---- bcomb = Wfc @ bo + bfc ----
    float* red = sh;
    int r = tid >> 4, c = tid & 15;
    int row = (bx - 16) * 16 + r;
    float s = 0.0f;
    for (int k = c; k < 256; k += 16) s = fmaf(Wfc[(size_t)row * 256 + k], bo[k], s);
    red[tid] = s;
    __syncthreads();
    if (c == 0) {
      float t = 0.0f;
#pragma unroll
      for (int i = 0; i < 16; ++i) t += red[r * 16 + i];
      bcomb[row] = t + bfc[row];
    }
  } else {
    // ---- split fp32 -> bf16 h + residual l ----
    int g = (bx - 32) * 256 + tid;
    const float* src;
    __bf16 *dh, *dl;
    if (g < 131072) {                     // x: 1,048,576 floats
      src = x + (size_t)g * 8; dh = xh + (size_t)g * 8; dl = xl + (size_t)g * 8;
    } else {
      int e = g - 131072;                 // 0..24575
      int wsel = e >> 13;
      int inner = (e & 8191) * 8;
      src = (wsel == 0 ? Wq : (wsel == 1 ? Wk : Wv)) + inner;
      dh = Ws + wsel * 131072 + inner;
      dl = Ws + wsel * 131072 + 65536 + inner;
    }
    union { __bf16 h[8]; uint4 u; } ph, pl;
#pragma unroll
    for (int i = 0; i < 2; ++i) {
      float4 v = *(const float4*)(src + i * 4);
      float vv[4] = {v.x, v.y, v.z, v.w};
#pragma unroll
      for (int j = 0; j < 4; ++j) {
        __bf16 hb = (__bf16)vv[j];
        ph.h[i * 4 + j] = hb;
        pl.h[i * 4 + j] = (__bf16)(vv[j] - (float)hb);
      }
    }
    *(uint4*)dh = ph.u;
    *(uint4*)dl = pl.u;
  }
}

// ---------------------------------------------------------------------------
// Fused QKV projection, split-bf16 MFMA. Grid (64, 12), 4 waves.
__global__ __launch_bounds__(256)
void gemm_qkv_mfma(const __bf16* __restrict__ xh, const __bf16* __restrict__ xl,
                   const __bf16* __restrict__ Ws,
                   const float* __restrict__ bq, const float* __restrict__ bk,
                   const float* __restrict__ bv,
                   float* __restrict__ Qb, float* __restrict__ Kb,
                   float* __restrict__ Vb) {
  const int tid = threadIdx.x, w = tid >> 6, lane = tid & 63;
  const int l15 = lane & 15, lg = lane >> 4;
  const int m0 = blockIdx.x * 64, nb = blockIdx.y;
  const int wsel = nb >> 2;
  const int n256b = (nb & 3) * 64;
  const __bf16* Wh = Ws + wsel * 131072;
  const __bf16* Wl = Wh + 65536;
  const int arow = m0 + w * 16 + l15;
  const __bf16* axh = xh + (size_t)arow * 256 + lg * 8;
  const __bf16* axl = xl + (size_t)arow * 256 + lg * 8;
  f32x4 acc0 = {0,0,0,0}, acc1 = {0,0,0,0}, acc2 = {0,0,0,0}, acc3 = {0,0,0,0};
#pragma unroll
  for (int k0 = 0; k0 < 256; k0 += 32) {
    bf16x8 ah = *(const bf16x8*)(axh + k0);
    bf16x8 al = *(const bf16x8*)(axl + k0);
#pragma unroll
    for (int g = 0; g < 4; ++g) {
      const size_t br = (size_t)(n256b + g * 16 + l15) * 256 + lg * 8 + k0;
      bf16x8 bh = *(const bf16x8*)(Wh + br);
      bf16x8 bl = *(const bf16x8*)(Wl + br);
      f32x4& acc = g == 0 ? acc0 : (g == 1 ? acc1 : (g == 2 ? acc2 : acc3));
      acc = __builtin_amdgcn_mfma_f32_16x16x32_bf16(ah, bh, acc, 0, 0, 0);
      acc = __builtin_amdgcn_mfma_f32_16x16x32_bf16(al, bh, acc, 0, 0, 0);
      acc = __builtin_amdgcn_mfma_f32_16x16x32_bf16(ah, bl, acc, 0, 0, 0);
    }
  }
  const float* bias = wsel == 0 ? bq : (wsel == 1 ? bk : bv);
  float* C = wsel == 0 ? Qb : (wsel == 1 ? Kb : Vb);
#pragma unroll
  for (int g = 0; g < 4; ++g) {
    const f32x4& acc = g == 0 ? acc0 : (g == 1 ? acc1 : (g == 2 ? acc2 : acc3));
    int n256 = n256b + g * 16 + l15;
    float bval = bias[n256];
    int h = n256 >> 5, d = n256 & 31;
#pragma unroll
    for (int r = 0; r < 4; ++r) {
      int m = m0 + w * 16 + lg * 4 + r;
      int b = m >> 11, s = m & 2047;
      C[((size_t)((b << 3) + h) << 16) + (size_t)s * 32 + d] = acc[r] + bval;
    }
  }
}

// ---------------------------------------------------------------------------
// K3: fused {prep_qk (blocks 0-255, K-blocks also reduce kkmin/Bkmax)}
//     {prep_vt (256-767)} {vsum from fp32 V (768-895)}.
__global__ __launch_bounds__(256)
void k3_prep(const float* __restrict__ Qf, const float* __restrict__ Kf,
             const float* __restrict__ Vf,
             __bf16* __restrict__ Qbf, __bf16* __restrict__ Kbf,
             __bf16* __restrict__ Vt,
             float4* __restrict__ qtab4, float4* __restrict__ ktab4,
             float* __restrict__ Vsum, float2* __restrict__ Kred) {
  __shared__ float2 red2[256];
  const int bx = blockIdx.x, tid = threadIdx.x;
  if (bx < 256) {
    // ---- expmap0 -> bf16 rows + tables ----
    int idx = bx * 256 + tid;                 // 0..65535
    const bool isQ = idx < 32768;
    const int i2 = isQ ? idx : idx - 32768;
    const float* src = (isQ ? Qf : Kf) + (size_t)i2 * 32;
    __bf16* dst = (isQ ? Qbf : Kbf) + (size_t)i2 * 32;
    float v[32];
    float ss = 0.0f;
#pragma unroll
    for (int i = 0; i < 8; ++i) {
      float4 v4 = *(const float4*)&src[i * 4];
      v[i*4+0] = v4.x; v[i*4+1] = v4.y; v[i*4+2] = v4.z; v[i*4+3] = v4.w;
      ss = fmaf(v4.x, v4.x, ss); ss = fmaf(v4.y, v4.y, ss);
      ss = fmaf(v4.z, v4.z, ss); ss = fmaf(v4.w, v4.w, ss);
    }
    ss = fmaxf(ss, 1e-12f);
    float x  = sqrtf(ss);
    float ex = fast_exp2(-2.8853900817779268f * x);     // e^{-2x}
    float opex = 1.0f + ex;
    float th = (1.0f - ex) / opex;
    float sc = th / x;
    float qq = th * th;
    float Bv = 4.0f * ex / (opex * opex);                // 1 - qq, exact
    float lgB = 2.0f - 2.8853900817779268f * x - 2.0f * fast_log2(opex);
    if (isQ) qtab4[i2] = float4{qq, ALPHA * lgB, Bv, 0.0f};
    else     ktab4[i2] = float4{qq, Bv, ALPHA * lgB, 0.0f};
    union { __bf16 h[8]; uint4 u; } pk;
#pragma unroll
    for (int blk = 0; blk < 4; ++blk) {
#pragma unroll
      for (int j = 0; j < 8; ++j) pk.h[j] = (__bf16)(v[blk * 8 + j] * sc);
      *(uint4*)(dst + blk * 8) = pk.u;
    }
    if (!isQ) {   // block-uniform: blocks 128..255 are all-K
      red2[tid] = float2{qq, Bv};
      __syncthreads();
      for (int s = 128; s > 0; s >>= 1) {
        if (tid < s) {
          red2[tid].x = fminf(red2[tid].x, red2[tid + s].x);
          red2[tid].y = fmaxf(red2[tid].y, red2[tid + s].y);
        }
        __syncthreads();
      }
      if (tid == 0) Kred[bx - 128] = red2[0];  // 8 partials per bh
    }
  } else if (bx < 768) {
    // ---- V[bh][t][dh] fp32 -> V^T[bh][dh][t] bf16 ----
    int g = (bx - 256) * 256 + tid;           // 0..131071
    int bh = g >> 13, rem = g & 8191;
    int tb = rem >> 5, dh = rem & 31;
    const float* src = Vf + (((size_t)bh * 2048 + tb * 8) * 32) + dh;
    union { __bf16 h[8]; uint4 u; } pk;
#pragma unroll
    for (int e = 0; e < 8; ++e) pk.h[e] = (__bf16)src[e * 32];
    *(uint4*)(Vt + ((size_t)bh * 32 + dh) * 2048 + tb * 8) = pk.u;
  } else {
    // ---- Vsum32[bh][t32][dh] = sum_{j<32} V[bh][t32*32+j][dh] (fp32) ----
    int g = (bx - 768) * 256 + tid;           // 0..32767
    int bh = g >> 11, rem = g & 2047;
    int t32 = rem >> 5, dh = rem & 31;
    const float* src = Vf + (((size_t)bh * 2048 + t32 * 32) * 32) + dh;
    float s = 0.0f;
#pragma unroll
    for (int j = 0; j < 32; ++j) s += src[j * 32];
    Vsum[((size_t)bh * 64 + t32) * 32 + dh] = s;
  }
}

// ---------------------------------------------------------------------------
// Flash attention, scalar-conservative clip test, barrier-free, with explicit
// 2-deep load pipeline (next tile's loads issue before current tile's branchy
// compute). Grid (32, 4, 16), 4 waves.
__global__ __launch_bounds__(256)
void attn_mfma(const __bf16* __restrict__ Qbf, const __bf16* __restrict__ Kbf,
               const __bf16* __restrict__ Vt,  const float4* __restrict__ qtab4,
               const float4* __restrict__ ktab4, const float* __restrict__ Vsum,
               const float2* __restrict__ Kred,
               float* __restrict__ PN, float* __restrict__ PD) {
  __shared__ __bf16 Pt[4][16][72];   // rare-path per-wave P^T (wave-private)
  const int tid = threadIdx.x;
  const int wid = tid >> 6, lane = tid & 63;
  const int l15 = lane & 15, lg = lane >> 4;
  const int tc = blockIdx.y, bh = blockIdx.z;
  const int sblk = blockIdx.x;
  const int s0 = sblk * 64 + wid * 16;

  bf16x8 qfrag = *(const bf16x8*)(Qbf + ((size_t)bh * 2048 + s0 + l15) * 32 + lg * 8);
  float4 qt = qtab4[bh * 2048 + s0 + l15];
  const float qq = qt.x, Bq = qt.z;
  const float eminRow = EMIN - qt.y;
  const float wclipf = (float)(__bf16)fast_exp2(eminRow);   // bf16-quantized
  float wrow[4];
#pragma unroll
  for (int r = 0; r < 4; ++r)
    wrow[r] = (float)(__bf16)fast_exp2(EMIN - qtab4[bh * 2048 + s0 + lg * 4 + r].y);

  // conservative per-row clip threshold: max(S) <= thr_all => whole subtile clips
  float kkmin = 1.0f, bkmax = 0.0f;
#pragma unroll
  for (int j = 0; j < 8; ++j) {
    float2 kr = Kred[bh * 8 + j];
    kkmin = fminf(kkmin, kr.x);
    bkmax = fmaxf(bkmax, kr.y);
  }
  const float thr_all = fmaf(0.5f * qq, kkmin,
                             fmaf(Bq * NEG_INV_2CHI, bkmax, 0.5f));

  const __bf16* Kbase = Kbf + ((size_t)bh << 16);
  const __bf16* Vbase = Vt + ((size_t)bh << 16);
  const float4* Tk = ktab4 + bh * 2048;
  const float*  VsBase = Vsum + (size_t)bh * 64 * 32;
  __bf16* Pw = &Pt[wid][0][0];

  f32x4 accO0 = {0.f, 0.f, 0.f, 0.f};
  f32x4 accO1 = {0.f, 0.f, 0.f, 0.f};
  float den = 0.0f;
  int nclip = 0;
  const f32x4 zero = {0.f, 0.f, 0.f, 0.f};
  const int tbeg = tc * 512;
  const int stag = sblk & 7;

  // ---- 2-deep pipeline: named A/B register sets, fully unrolled ----
  bf16x8 kfA0, kfA1, kfA2, kfA3, kfB0, kfB1, kfB2, kfB3;
  float vA0, vA1, vA2, vA3, vB0, vB1, vB2, vB3;

#define LOAD_SET(K0, K1, K2, K3, V0, V1, V2, V3, T0)                          \
  {                                                                           \
    const int _t = (T0);                                                      \
    K0 = *(const bf16x8*)(Kbase + (size_t)(_t + 0 * 16 + l15) * 32 + lg * 8); \
    K1 = *(const bf16x8*)(Kbase + (size_t)(_t + 1 * 16 + l15) * 32 + lg * 8); \
    K2 = *(const bf16x8*)(Kbase + (size_t)(_t + 2 * 16 + l15) * 32 + lg * 8); \
    K3 = *(const bf16x8*)(Kbase + (size_t)(_t + 3 * 16 + l15) * 32 + lg * 8); \
    const int _ti = _t >> 5;                                                  \
    V0 = VsBase[_ti * 32 + l15];                                              \
    V1 = VsBase[(_ti + 1) * 32 + l15];                                        \
    V2 = VsBase[_ti * 32 + 16 + l15];                                         \
    V3 = VsBase[(_ti + 1) * 32 + 16 + l15];                                   \
  }

#define COMPUTE_SET(K0, K1, K2, K3, V0, V1, V2, V3, T0)                       \
  {                                                                           \
    const int _t0 = (T0);                                                     \
    __builtin_amdgcn_s_setprio(1);                                            \
    _Pragma("unroll")                                                         \
    for (int h = 0; h < 2; ++h) {                                             \
      f32x4 S[2];                                                             \
      bool ok = true;                                                         \
      _Pragma("unroll")                                                       \
      for (int s2 = 0; s2 < 2; ++s2) {                                        \
        bf16x8 kf = (h == 0) ? (s2 == 0 ? K0 : K1) : (s2 == 0 ? K2 : K3);     \
        f32x4 Sv = __builtin_amdgcn_mfma_f32_16x16x32_bf16(kf, qfrag, zero,   \
                                                           0, 0, 0);          \
        S[s2] = Sv;                                                           \
        float m = fmaxf(fmaxf(Sv[0], Sv[1]), fmaxf(Sv[2], Sv[3]));            \
        ok &= (m <= thr_all);                                                 \
      }                                                                       \
      if (__all((int)ok)) {                                                   \
        ++nclip;                                                              \
        const float vsA = h ? V1 : V0;                                        \
        const float vsB = h ? V3 : V2;                                        \
        _Pragma("unroll")                                                     \
        for (int r = 0; r < 4; ++r) {                                         \
          accO0[r] = fmaf(wrow[r], vsA, accO0[r]);                            \
          accO1[r] = fmaf(wrow[r], vsB, accO1[r]);                            \
        }                                                                     \
      } else {                                                                \
        _Pragma("unroll")                                                     \
        for (int s2 = 0; s2 < 2; ++s2) {                                      \
          const int sub = h * 2 + s2;                                         \
          const int tk = _t0 + sub * 16 + lg * 4;                             \
          f32x4 Sv = S[s2];                                                   \
          float w[4];                                                         \
          _Pragma("unroll")                                                   \
          for (int r = 0; r < 4; ++r) {                                       \
            float4 T = Tk[tk + r];                                            \
            float qk2 = Sv[r] + Sv[r];                                        \
            float u = (qq + T.x) - qk2;                                       \
            float d = fmaf(qq, T.x, 1.0f) - qk2;                              \
            float p = fmaxf(u * d, 0.0f);                                     \
            float sq = sqrtf(p);                                              \
            float m2 = fmaf(2.0f, sq, u + d);                                 \
            float e = fmaf(-ALPHA, fast_log2(m2), T.z);                       \
            e = fmaxf(e, eminRow);                                            \
            w[r] = fast_exp2(e);                                              \
          }                                                                   \
          den += (w[0] + w[1]) + (w[2] + w[3]);                               \
          union { __bf16 hh[4]; uint2 u2; } pk;                               \
          pk.hh[0] = (__bf16)w[0]; pk.hh[1] = (__bf16)w[1];                   \
          pk.hh[2] = (__bf16)w[2]; pk.hh[3] = (__bf16)w[3];                   \
          *(uint2*)&Pw[l15 * 72 + sub * 16 + lg * 4] = pk.u2;                 \
        }                                                                     \
        bf16x8 pfrag = *(const bf16x8*)&Pw[l15 * 72 + h * 32 + lg * 8];       \
        bf16x8 v0 = *(const bf16x8*)(Vbase + (size_t)l15 * 2048 + _t0 +       \
                                     h * 32 + lg * 8);                        \
        bf16x8 v1 = *(const bf16x8*)(Vbase + (size_t)(16 + l15) * 2048 +      \
                                     _t0 + h * 32 + lg * 8);                  \
        accO0 = __builtin_amdgcn_mfma_f32_16x16x32_bf16(pfrag, v0, accO0,     \
                                                        0, 0, 0);             \
        accO1 = __builtin_amdgcn_mfma_f32_16x16x32_bf16(pfrag, v1, accO1,     \
                                                        0, 0, 0);             \
      }                                                                       \
    }                                                                         \
    __builtin_amdgcn_s_setprio(0);                                            \
  }

  // prologue: load tile 0 into set A
  LOAD_SET(kfA0, kfA1, kfA2, kfA3, vA0, vA1, vA2, vA3,
           tbeg + ((stag & 7) << 6));

#pragma unroll
  for (int i = 0; i < 8; ++i) {
    const int tcur = tbeg + (((i + stag) & 7) << 6);
    const int tnxt = tbeg + (((i + 1 + stag) & 7) << 6);
    if ((i & 1) == 0) {
      if (i < 7) LOAD_SET(kfB0, kfB1, kfB2, kfB3, vB0, vB1, vB2, vB3, tnxt);
      COMPUTE_SET(kfA0, kfA1, kfA2, kfA3, vA0, vA1, vA2, vA3, tcur);
    } else {
      if (i < 7) LOAD_SET(kfA0, kfA1, kfA2, kfA3, vA0, vA1, vA2, vA3, tnxt);
      COMPUTE_SET(kfB0, kfB1, kfB2, kfB3, vB0, vB1, vB2, vB3, tcur);
    }
  }
#undef LOAD_SET
#undef COMPUTE_SET

  den = fmaf(8.0f * wclipf, (float)nclip, den);
  den += __shfl_xor(den, 16);
  den += __shfl_xor(den, 32);
  size_t pbase = ((size_t)tc * 16 + bh) * 2048;
  if (lg == 0) PD[pbase + s0 + l15] = den;
#pragma unroll
  for (int r = 0; r < 4; ++r) {
    int sl = lg * 4 + r;
    size_t row = (pbase + s0 + sl) * 32;
    PN[row + l15]      = accO0[r];
    PN[row + 16 + l15] = accO1[r];
  }
}

// ---------------------------------------------------------------------------
// Sum the 4 t-chunk partials, normalize, write AO as bf16 (h, l) pair.
__global__ __launch_bounds__(256)
void combine4(const float* __restrict__ PN, const float* __restrict__ PD,
              __bf16* __restrict__ AOh, __bf16* __restrict__ AOl) {
  int idx = blockIdx.x * 256 + threadIdx.x;   // 0..32767 = (bh, s)
  int bh = idx >> 11, s = idx & 2047;
  int b = bh >> 3, h = bh & 7;
  float den = 0.0f;
#pragma unroll
  for (int c = 0; c < 4; ++c) den += PD[((size_t)c * 16 + bh) * 2048 + s];
  float r = 1.0f / den;
  size_t ob = ((size_t)b * 2048 + s) * 256 + h * 32;
#pragma unroll
  for (int i = 0; i < 8; ++i) {
    float4 sum = {0.0f, 0.0f, 0.0f, 0.0f};
#pragma unroll
    for (int c = 0; c < 4; ++c) {
      float4 v = *(const float4*)&PN[((((size_t)c * 16 + bh) * 2048 + s) * 32) + i * 4];
      sum.x += v.x; sum.y += v.y; sum.z += v.z; sum.w += v.w;
    }
    float vv[4] = {sum.x * r, sum.y * r, sum.z * r, sum.w * r};
    union { __bf16 h4[4]; uint2 u; } ph, pl;
#pragma unroll
    for (int j = 0; j < 4; ++j) {
      __bf16 hb = (__bf16)vv[j];
      ph.h4[j] = hb;
      pl.h4[j] = (__bf16)(vv[j] - (float)hb);
    }
    *(uint2*)(AOh + ob + i * 4) = ph.u;
    *(uint2*)(AOl + ob + i * 4) = pl.u;
  }
}

// ---------------------------------------------------------------------------
// Output projection, split-bf16 MFMA: out = AO @ Wcomb^T + bcomb. Grid (64,4).
__global__ __launch_bounds__(256)
void gemm_out_mfma(const __bf16* __restrict__ aoh, const __bf16* __restrict__ aol,
                   const __bf16* __restrict__ Wch, const __bf16* __restrict__ Wcl,
                   const float* __restrict__ bcomb, float* __restrict__ out) {
  const int tid = threadIdx.x, w = tid >> 6, lane = tid & 63;
  const int l15 = lane & 15, lg = lane >> 4;
  const int m0 = blockIdx.x * 64, n0 = blockIdx.y * 64;
  const int arow = m0 + w * 16 + l15;
  const __bf16* axh = aoh + (size_t)arow * 256 + lg * 8;
  const __bf16* axl = aol + (size_t)arow * 256 + lg * 8;
  f32x4 acc0 = {0,0,0,0}, acc1 = {0,0,0,0}, acc2 = {0,0,0,0}, acc3 = {0,0,0,0};
#pragma unroll
  for (int k0 = 0; k0 < 256; k0 += 32) {
    bf16x8 ah = *(const bf16x8*)(axh + k0);
    bf16x8 al = *(const bf16x8*)(axl + k0);
#pragma unroll
    for (int g = 0; g < 4; ++g) {
      const size_t br = (size_t)(n0 + g * 16 + l15) * 256 + lg * 8 + k0;
      bf16x8 bh = *(const bf16x8*)(Wch + br);
      bf16x8 bl = *(const bf16x8*)(Wcl + br);
      f32x4& acc = g == 0 ? acc0 : (g == 1 ? acc1 : (g == 2 ? acc2 : acc3));
      acc = __builtin_amdgcn_mfma_f32_16x16x32_bf16(ah, bh, acc, 0, 0, 0);
      acc = __builtin_amdgcn_mfma_f32_16x16x32_bf16(al, bh, acc, 0, 0, 0);
      acc = __builtin_amdgcn_mfma_f32_16x16x32_bf16(ah, bl, acc, 0, 0, 0);
    }
  }
#pragma unroll
  for (int g = 0; g < 4; ++g) {
    const f32x4& acc = g == 0 ? acc0 : (g == 1 ? acc1 : (g == 2 ? acc2 : acc3));
    int n = n0 + g * 16 + l15;
    float bval = bcomb[n];
#pragma unroll
    for (int r = 0; r < 4; ++r) {
      int m = m0 + w * 16 + lg * 4 + r;
      out[(size_t)m * 256 + n] = acc[r] + bval;
    }
  }
}

// ---------------------------------------------------------------------------
extern "C" void kernel_launch(void* const* d_in, const int* in_sizes, int n_in,
                              void* d_out, int out_size, void* d_ws, size_t ws_size,
                              hipStream_t stream) {
  const float* x   = (const float*)d_in[0];
  const float* Wq  = (const float*)d_in[1];
  const float* bq  = (const float*)d_in[2];
  const float* Wk  = (const float*)d_in[3];
  const float* bk  = (const float*)d_in[4];
  const float* Wv  = (const float*)d_in[5];
  const float* bv  = (const float*)d_in[6];
  const float* Wo  = (const float*)d_in[7];
  const float* bo  = (const float*)d_in[8];
  const float* Wfc = (const float*)d_in[9];
  const float* bfc = (const float*)d_in[10];

  float* ws = (float*)d_ws;
  // Workspace layout (float offsets); ~41.7 MB total.
  float* Qb  = ws;                                      // 1M
  float* Kb  = ws + (1 << 20);                          // 1M
  float* Vb  = ws + (2 << 20);                          // 1M
  __bf16* Qbf = (__bf16*)(ws + (3 << 20));              // 1M bf16
  __bf16* Kbf = (__bf16*)(ws + (3 << 20) + (1 << 19));  // 1M bf16
  __bf16* Vtb = (__bf16*)(ws + (4 << 20));              // 1M bf16
  float4* qtab4 = (float4*)(ws + (4 << 20) + (1 << 19));             // 128K f
  float4* ktab4 = (float4*)(ws + (4 << 20) + (1 << 19) + (1 << 17)); // 128K f
  float*  Vsum  = ws + (4 << 20) + (1 << 19) + (2 << 17);            // 32K f
  __bf16* Wch   = (__bf16*)(Vsum + (1 << 15));          // 64K bf16 (32K f)
  __bf16* Wcl   = Wch + 65536;                          // 64K bf16
  float*  bcomb = Vsum + (1 << 15) + (1 << 16);         // 256
  float2* Kred  = (float2*)(bcomb + 256);               // 128 float2
  __bf16* xh = (__bf16*)(ws + (5 << 20));               // 1M bf16
  __bf16* xl = (__bf16*)(ws + (5 << 20) + (1 << 19));   // 1M bf16
  __bf16* Wsplit = (__bf16*)(ws + (6 << 20));           // 393216 bf16
  float* PN = ws + (6 << 20) + (1 << 18);               // 4M
  float* PD = PN + (4 << 20);                           // 128K
  __bf16* AOh = (__bf16*)ws;                            // reuse Qb slab
  __bf16* AOl = (__bf16*)(ws + (1 << 19));              // reuse Qb slab

  dim3 blk(256);
  k1_misc<<<dim3(640), blk, 0, stream>>>(x, Wq, Wk, Wv, Wfc, Wo, bo, bfc,
                                         xh, xl, Wsplit, Wch, Wcl, bcomb);
  gemm_qkv_mfma<<<dim3(64, 12), blk, 0, stream>>>(xh, xl, Wsplit, bq, bk, bv,
                                                  Qb, Kb, Vb);
  k3_prep<<<dim3(896), blk, 0, stream>>>(Qb, Kb, Vb, Qbf, Kbf, Vtb,
                                         qtab4, ktab4, Vsum, Kred);
  attn_mfma<<<dim3(32, 4, 16), blk, 0, stream>>>(Qbf, Kbf, Vtb, qtab4, ktab4,
                                                 Vsum, Kred, PN, PD);
  combine4<<<dim3(128), blk, 0, stream>>>(PN, PD, AOh, AOl);
  gemm_out_mfma<<<dim3(64, 4), blk, 0, stream>>>(AOh, AOl, Wch, Wcl, bcomb,
                                                 (float*)d_out);
}

// Round 14
// 105.794 us; speedup vs baseline: 1.0410x; 1.0410x over previous
//
#include <hip/hip_runtime.h>
#include <cstdint>
#include <cstddef>

// Poincare-ball (hyperbolic) attention block. B=2, S=2048, D=256, H=8, dh=32, c=1.
//
// Round 14 (vs round 13):
//  - gemm_qkv epilogue now FUSES the expmap prep for Q/K: block holds full
//    32-dh rows -> shfl-reduce ss, sech^2 chain in-register, writes bf16
//    Q/K + qtab/ktab + Kred partials directly (no fp32 Q/K round-trip; k3
//    shrinks to V-only).
//  - PN partials stored as bf16 (adds ~3e-5 error, halves partial traffic).
//  - attn otherwise identical to round 13 (Kred 32 partials/bh).

#define ALPHA 0.17677669529663687f   // 1/sqrt(32)
#define EMIN  -3.1129694f            // -ALPHA * log2((2-1e-5)/1e-5)  (clip)
#define CHI   1.95e-5f               // conservative 1-(1-1e-5)^2
#define NEG_INV_2CHI -25641.026f     // -1/(2*CHI)
#define TWOLOG2E 2.8853900817779268f // 2*log2(e)

typedef __bf16 bf16x8 __attribute__((ext_vector_type(8)));
typedef float  f32x4  __attribute__((ext_vector_type(4)));

__device__ __forceinline__ float fast_log2(float x) { return __builtin_amdgcn_logf(x); }
__device__ __forceinline__ float fast_exp2(float x) { return __builtin_amdgcn_exp2f(x); }

// ---------------------------------------------------------------------------
// K1: fused {Wcomb = Wfc@Wo (blocks 0-15)} {bcomb = Wfc@bo+bfc (16-31)}
//     {fp32->bf16 h/l splits of x, Wq, Wk, Wv (32-639)}.
__global__ __launch_bounds__(256)
void k1_misc(const float* __restrict__ x,   const float* __restrict__ Wq,
             const float* __restrict__ Wk,  const float* __restrict__ Wv,
             const float* __restrict__ Wfc, const float* __restrict__ Wo,
             const float* __restrict__ bo,  const float* __restrict__ bfc,
             __bf16* __restrict__ xh, __bf16* __restrict__ xl,
             __bf16* __restrict__ Ws, __bf16* __restrict__ Wch,
             __bf16* __restrict__ Wcl, float* __restrict__ bcomb) {
  __shared__ float sh[2 * 32 * 68];
  const int bx = blockIdx.x, tid = threadIdx.x;
  if (bx < 16) {
    float (*AsT)[68] = (float(*)[68])sh;
    float (*Bs)[68]  = (float(*)[68])(sh + 32 * 68);
    const int ty = tid >> 4, tx = tid & 15;
    const int m0 = (bx >> 2) * 64, n0 = (bx & 3) * 64;
    float acc[4][4] = {};
    for (int k0 = 0; k0 < 256; k0 += 32) {
#pragma unroll
      for (int jj = 0; jj < 2; ++jj) {
        int j = tid * 2 + jj;
        {
          int r = j >> 3, c4 = (j & 7) << 2;
          float4 av = *(const float4*)&Wfc[(size_t)(m0 + r) * 256 + k0 + c4];
          AsT[c4 + 0][r] = av.x; AsT[c4 + 1][r] = av.y;
          AsT[c4 + 2][r] = av.z; AsT[c4 + 3][r] = av.w;
        }
        {
          int r = j >> 4, c4 = (j & 15) << 2;
          *(float4*)&Bs[r][c4] = *(const float4*)&Wo[(size_t)(k0 + r) * 256 + n0 + c4];
        }
      }
      __syncthreads();
#pragma unroll
      for (int kk = 0; kk < 32; ++kk) {
        float4 a = *(const float4*)&AsT[kk][ty * 4];
        float4 b = *(const float4*)&Bs[kk][tx * 4];
        float av[4] = {a.x, a.y, a.z, a.w};
        float bv[4] = {b.x, b.y, b.z, b.w};
#pragma unroll
        for (int i = 0; i < 4; ++i)
#pragma unroll
          for (int j2 = 0; j2 < 4; ++j2)
            acc[i][j2] = fmaf(av[i], bv[j2], acc[i][j2]);
      }
      __syncthreads();
    }
#pragma unroll
    for (int i = 0; i < 4; ++i) {
      union { __bf16 h[4]; uint2 u; } ph, pl;
#pragma unroll
      for (int j = 0; j < 4; ++j) {
        __bf16 hb = (__bf16)acc[i][j];
        ph.h[j] = hb;
        pl.h[j] = (__bf16)(acc[i][j] - (float)hb);
      }
      size_t off = (size_t)(m0 + ty * 4 + i) * 256 + n0 + tx * 4;
      *(uint2*)(Wch + off) = ph.u;
      *(uint2*)(Wcl + off) = pl.u;
    }
  } else if (bx < 32) {
    float* red = sh;
    int r = tid >> 4, c = tid & 15;
    int row = (bx - 16) * 16 + r;
    float s = 0.0f;
    for (int k = c; k < 256; k += 16) s = fmaf(Wfc[(size_t)row * 256 + k], bo[k], s);
    red[tid] = s;
    __syncthreads();
    if (c == 0) {
      float t = 0.0f;
#pragma unroll
      for (int i = 0; i < 16; ++i) t += red[r * 16 + i];
      bcomb[row] = t + bfc[row];
    }
  } else {
    int g = (bx - 32) * 256 + tid;
    const float* src;
    __bf16 *dh, *dl;
    if (g < 131072) {
      src = x + (size_t)g * 8; dh = xh + (size_t)g * 8; dl = xl + (size_t)g * 8;
    } else {
      int e = g - 131072;
      int wsel = e >> 13;
      int inner = (e & 8191) * 8;
      src = (wsel == 0 ? Wq : (wsel == 1 ? Wk : Wv)) + inner;
      dh = Ws + wsel * 131072 + inner;
      dl = Ws + wsel * 131072 + 65536 + inner;
    }
    union { __bf16 h[8]; uint4 u; } ph, pl;
#pragma unroll
    for (int i = 0; i < 2; ++i) {
      float4 v = *(const float4*)(src + i * 4);
      float vv[4] = {v.x, v.y, v.z, v.w};
#pragma unroll
      for (int j = 0; j < 4; ++j) {
        __bf16 hb = (__bf16)vv[j];
        ph.h[i * 4 + j] = hb;
        pl.h[i * 4 + j] = (__bf16)(vv[j] - (float)hb);
      }
    }
    *(uint4*)dh = ph.u;
    *(uint4*)dl = pl.u;
  }
}

// ---------------------------------------------------------------------------
// Fused QKV projection + expmap prep, split-bf16 MFMA. Grid (64, 12), 4 waves.
// wsel 0/1 (Q/K): bias-add, per-row ss via shfl, sech^2 chain -> bf16 rows +
// tables (+ Kred partials for K). wsel 2 (V): fp32 head-major as before.
__global__ __launch_bounds__(256)
void gemm_qkv_mfma(const __bf16* __restrict__ xh, const __bf16* __restrict__ xl,
                   const __bf16* __restrict__ Ws,
                   const float* __restrict__ bq, const float* __restrict__ bk,
                   const float* __restrict__ bv,
                   __bf16* __restrict__ Qbf, __bf16* __restrict__ Kbf,
                   float* __restrict__ Vb,
                   float4* __restrict__ qtab4, float4* __restrict__ ktab4,
                   float2* __restrict__ Kred) {
  __shared__ float4 kredsh[4];
  const int tid = threadIdx.x, w = tid >> 6, lane = tid & 63;
  const int l15 = lane & 15, lg = lane >> 4;
  const int m0 = blockIdx.x * 64, nb = blockIdx.y;
  const int wsel = nb >> 2;
  const int n256b = (nb & 3) * 64;
  const __bf16* Wh = Ws + wsel * 131072;
  const __bf16* Wl = Wh + 65536;
  const int arow = m0 + w * 16 + l15;
  const __bf16* axh = xh + (size_t)arow * 256 + lg * 8;
  const __bf16* axl = xl + (size_t)arow * 256 + lg * 8;
  f32x4 acc0 = {0,0,0,0}, acc1 = {0,0,0,0}, acc2 = {0,0,0,0}, acc3 = {0,0,0,0};
#pragma unroll
  for (int k0 = 0; k0 < 256; k0 += 32) {
    bf16x8 ah = *(const bf16x8*)(axh + k0);
    bf16x8 al = *(const bf16x8*)(axl + k0);
#pragma unroll
    for (int g = 0; g < 4; ++g) {
      const size_t br = (size_t)(n256b + g * 16 + l15) * 256 + lg * 8 + k0;
      bf16x8 bh = *(const bf16x8*)(Wh + br);
      bf16x8 bl = *(const bf16x8*)(Wl + br);
      f32x4& acc = g == 0 ? acc0 : (g == 1 ? acc1 : (g == 2 ? acc2 : acc3));
      acc = __builtin_amdgcn_mfma_f32_16x16x32_bf16(ah, bh, acc, 0, 0, 0);
      acc = __builtin_amdgcn_mfma_f32_16x16x32_bf16(al, bh, acc, 0, 0, 0);
      acc = __builtin_amdgcn_mfma_f32_16x16x32_bf16(ah, bl, acc, 0, 0, 0);
    }
  }
  const float* bias = wsel == 0 ? bq : (wsel == 1 ? bk : bv);

  if (wsel == 2) {
    // ---- V: fp32 head-major output (unchanged) ----
#pragma unroll
    for (int g = 0; g < 4; ++g) {
      const f32x4& acc = g == 0 ? acc0 : (g == 1 ? acc1 : (g == 2 ? acc2 : acc3));
      int n256 = n256b + g * 16 + l15;
      float bval = bias[n256];
      int h = n256 >> 5, d = n256 & 31;
#pragma unroll
      for (int r = 0; r < 4; ++r) {
        int m = m0 + w * 16 + lg * 4 + r;
        int b = m >> 11, s = m & 2047;
        Vb[((size_t)((b << 3) + h) << 16) + (size_t)s * 32 + d] = acc[r] + bval;
      }
    }
    return;
  }

  // ---- Q/K: fused expmap prep ----
  const float bv0 = bias[n256b + 0 * 16 + l15];
  const float bv1 = bias[n256b + 1 * 16 + l15];
  const float bv2 = bias[n256b + 2 * 16 + l15];
  const float bv3 = bias[n256b + 3 * 16 + l15];
  float ssA[4], ssB[4];
#pragma unroll
  for (int r = 0; r < 4; ++r) {
    acc0[r] += bv0; acc1[r] += bv1; acc2[r] += bv2; acc3[r] += bv3;
    ssA[r] = acc0[r] * acc0[r] + acc1[r] * acc1[r];
    ssB[r] = acc2[r] * acc2[r] + acc3[r] * acc3[r];
  }
#pragma unroll
  for (int mk = 1; mk < 16; mk <<= 1) {
#pragma unroll
    for (int r = 0; r < 4; ++r) {
      ssA[r] += __shfl_xor(ssA[r], mk);
      ssB[r] += __shfl_xor(ssB[r], mk);
    }
  }
  float scA[4], qqA[4], BvA[4], lgA[4];
  float scB[4], qqB[4], BvB[4], lgB_[4];
#pragma unroll
  for (int r = 0; r < 4; ++r) {
    {
      float ss = fmaxf(ssA[r], 1e-12f);
      float xv = sqrtf(ss);
      float ex = fast_exp2(-TWOLOG2E * xv);
      float opex = 1.0f + ex;
      float th = (1.0f - ex) / opex;
      scA[r] = th / xv;
      qqA[r] = th * th;
      BvA[r] = 4.0f * ex / (opex * opex);
      lgA[r] = 2.0f - TWOLOG2E * xv - 2.0f * fast_log2(opex);
    }
    {
      float ss = fmaxf(ssB[r], 1e-12f);
      float xv = sqrtf(ss);
      float ex = fast_exp2(-TWOLOG2E * xv);
      float opex = 1.0f + ex;
      float th = (1.0f - ex) / opex;
      scB[r] = th / xv;
      qqB[r] = th * th;
      BvB[r] = 4.0f * ex / (opex * opex);
      lgB_[r] = 2.0f - TWOLOG2E * xv - 2.0f * fast_log2(opex);
    }
  }
  __bf16* dst = wsel == 0 ? Qbf : Kbf;
  float4* tab = wsel == 0 ? qtab4 : ktab4;
  const int b = m0 >> 11;                    // block-uniform (64-row blocks)
  const int headA = n256b >> 5, headB = headA + 1;
  const int bhA = (b << 3) + headA, bhB = (b << 3) + headB;
  const int sbase = (m0 & 2047) + w * 16 + lg * 4;
#pragma unroll
  for (int r = 0; r < 4; ++r) {
    int s = sbase + r;
    size_t baseA = ((size_t)bhA * 2048 + s) * 32;
    size_t baseB = ((size_t)bhB * 2048 + s) * 32;
    dst[baseA + l15]      = (__bf16)(acc0[r] * scA[r]);
    dst[baseA + 16 + l15] = (__bf16)(acc1[r] * scA[r]);
    dst[baseB + l15]      = (__bf16)(acc2[r] * scB[r]);
    dst[baseB + 16 + l15] = (__bf16)(acc3[r] * scB[r]);
    if (l15 == 0) {
      if (wsel == 0) {
        tab[(size_t)bhA * 2048 + s] = float4{qqA[r], ALPHA * lgA[r], BvA[r], 0.0f};
        tab[(size_t)bhB * 2048 + s] = float4{qqB[r], ALPHA * lgB_[r], BvB[r], 0.0f};
      } else {
        tab[(size_t)bhA * 2048 + s] = float4{qqA[r], BvA[r], ALPHA * lgA[r], 0.0f};
        tab[(size_t)bhB * 2048 + s] = float4{qqB[r], BvB[r], ALPHA * lgB_[r], 0.0f};
      }
    }
  }
  if (wsel == 1) {
    // per-head (kkmin, Bkmax) partial over this block's 64 rows
    float mnA = fminf(fminf(qqA[0], qqA[1]), fminf(qqA[2], qqA[3]));
    float mxA = fmaxf(fmaxf(BvA[0], BvA[1]), fmaxf(BvA[2], BvA[3]));
    float mnB = fminf(fminf(qqB[0], qqB[1]), fminf(qqB[2], qqB[3]));
    float mxB = fmaxf(fmaxf(BvB[0], BvB[1]), fmaxf(BvB[2], BvB[3]));
    mnA = fminf(mnA, __shfl_xor(mnA, 16)); mnA = fminf(mnA, __shfl_xor(mnA, 32));
    mxA = fmaxf(mxA, __shfl_xor(mxA, 16)); mxA = fmaxf(mxA, __shfl_xor(mxA, 32));
    mnB = fminf(mnB, __shfl_xor(mnB, 16)); mnB = fminf(mnB, __shfl_xor(mnB, 32));
    mxB = fmaxf(mxB, __shfl_xor(mxB, 16)); mxB = fmaxf(mxB, __shfl_xor(mxB, 32));
    if (lane == 0) kredsh[w] = float4{mnA, mxA, mnB, mxB};
    __syncthreads();
    if (tid == 0) {
      float4 a = kredsh[0], b4 = kredsh[1], c4 = kredsh[2], d4 = kredsh[3];
      float MnA = fminf(fminf(a.x, b4.x), fminf(c4.x, d4.x));
      float MxA = fmaxf(fmaxf(a.y, b4.y), fmaxf(c4.y, d4.y));
      float MnB = fminf(fminf(a.z, b4.z), fminf(c4.z, d4.z));
      float MxB = fmaxf(fmaxf(a.w, b4.w), fmaxf(c4.w, d4.w));
      int bx31 = blockIdx.x & 31;
      Kred[bhA * 32 + bx31] = float2{MnA, MxA};
      Kred[bhB * 32 + bx31] = float2{MnB, MxB};
    }
  }
}

// ---------------------------------------------------------------------------
// K3v: V-only prep. Blocks 0-511: V fp32 -> V^T bf16. Blocks 512-639: Vsum32.
__global__ __launch_bounds__(256)
void k3v(const float* __restrict__ Vf, __bf16* __restrict__ Vt,
         float* __restrict__ Vsum) {
  const int bx = blockIdx.x, tid = threadIdx.x;
  if (bx < 512) {
    int g = bx * 256 + tid;                   // 0..131071
    int bh = g >> 13, rem = g & 8191;
    int tb = rem >> 5, dh = rem & 31;
    const float* src = Vf + (((size_t)bh * 2048 + tb * 8) * 32) + dh;
    union { __bf16 h[8]; uint4 u; } pk;
#pragma unroll
    for (int e = 0; e < 8; ++e) pk.h[e] = (__bf16)src[e * 32];
    *(uint4*)(Vt + ((size_t)bh * 32 + dh) * 2048 + tb * 8) = pk.u;
  } else {
    int g = (bx - 512) * 256 + tid;           // 0..32767
    int bh = g >> 11, rem = g & 2047;
    int t32 = rem >> 5, dh = rem & 31;
    const float* src = Vf + (((size_t)bh * 2048 + t32 * 32) * 32) + dh;
    float s = 0.0f;
#pragma unroll
    for (int j = 0; j < 32; ++j) s += src[j * 32];
    Vsum[((size_t)bh * 64 + t32) * 32 + dh] = s;
  }
}

// ---------------------------------------------------------------------------
// Flash attention (round-13 structure; Kred 32 partials/bh; PN stored bf16).
// Grid (32, 4, 16), 4 waves.
__global__ __launch_bounds__(256)
void attn_mfma(const __bf16* __restrict__ Qbf, const __bf16* __restrict__ Kbf,
               const __bf16* __restrict__ Vt,  const float4* __restrict__ qtab4,
               const float4* __restrict__ ktab4, const float* __restrict__ Vsum,
               const float2* __restrict__ Kred,
               __bf16* __restrict__ PNb, float* __restrict__ PD) {
  __shared__ __bf16 Pt[4][16][72];   // rare-path per-wave P^T (wave-private)
  const int tid = threadIdx.x;
  const int wid = tid >> 6, lane = tid & 63;
  const int l15 = lane & 15, lg = lane >> 4;
  const int tc = blockIdx.y, bh = blockIdx.z;
  const int sblk = blockIdx.x;
  const int s0 = sblk * 64 + wid * 16;

  bf16x8 qfrag = *(const bf16x8*)(Qbf + ((size_t)bh * 2048 + s0 + l15) * 32 + lg * 8);
  float4 qt = qtab4[bh * 2048 + s0 + l15];
  const float qq = qt.x, Bq = qt.z;
  const float eminRow = EMIN - qt.y;
  const float wclipf = (float)(__bf16)fast_exp2(eminRow);   // bf16-quantized
  float wrow[4];
#pragma unroll
  for (int r = 0; r < 4; ++r)
    wrow[r] = (float)(__bf16)fast_exp2(EMIN - qtab4[bh * 2048 + s0 + lg * 4 + r].y);

  // conservative per-row clip threshold from 32 per-bh partials
  float kkmin = 1.0f, bkmax = 0.0f;
#pragma unroll
  for (int j = 0; j < 32; ++j) {
    float2 kr = Kred[bh * 32 + j];
    kkmin = fminf(kkmin, kr.x);
    bkmax = fmaxf(bkmax, kr.y);
  }
  const float thr_all = fmaf(0.5f * qq, kkmin,
                             fmaf(Bq * NEG_INV_2CHI, bkmax, 0.5f));

  const __bf16* Kbase = Kbf + ((size_t)bh << 16);
  const __bf16* Vbase = Vt + ((size_t)bh << 16);
  const float4* Tk = ktab4 + bh * 2048;
  const float*  VsBase = Vsum + (size_t)bh * 64 * 32;
  __bf16* Pw = &Pt[wid][0][0];

  f32x4 accO0 = {0.f, 0.f, 0.f, 0.f};
  f32x4 accO1 = {0.f, 0.f, 0.f, 0.f};
  float den = 0.0f;
  int nclip = 0;
  const f32x4 zero = {0.f, 0.f, 0.f, 0.f};
  const int tbeg = tc * 512;
  const int stag = sblk & 7;

  bf16x8 kfA0, kfA1, kfA2, kfA3, kfB0, kfB1, kfB2, kfB3;
  float vA0, vA1, vA2, vA3, vB0, vB1, vB2, vB3;

#define LOAD_SET(K0, K1, K2, K3, V0, V1, V2, V3, T0)                          \
  {                                                                           \
    const int _t = (T0);                                                      \
    K0 = *(const bf16x8*)(Kbase + (size_t)(_t + 0 * 16 + l15) * 32 + lg * 8); \
    K1 = *(const bf16x8*)(Kbase + (size_t)(_t + 1 * 16 + l15) * 32 + lg * 8); \
    K2 = *(const bf16x8*)(Kbase + (size_t)(_t + 2 * 16 + l15) * 32 + lg * 8); \
    K3 = *(const bf16x8*)(Kbase + (size_t)(_t + 3 * 16 + l15) * 32 + lg * 8); \
    const int _ti = _t >> 5;                                                  \
    V0 = VsBase[_ti * 32 + l15];                                              \
    V1 = VsBase[(_ti + 1) * 32 + l15];                                        \
    V2 = VsBase[_ti * 32 + 16 + l15];                                         \
    V3 = VsBase[(_ti + 1) * 32 + 16 + l15];                                   \
  }

#define COMPUTE_SET(K0, K1, K2, K3, V0, V1, V2, V3, T0)                       \
  {                                                                           \
    const int _t0 = (T0);                                                     \
    __builtin_amdgcn_s_setprio(1);                                            \
    _Pragma("unroll")                                                         \
    for (int h = 0; h < 2; ++h) {                                             \
      f32x4 S[2];                                                             \
      bool ok = true;                                                         \
      _Pragma("unroll")                                                       \
      for (int s2 = 0; s2 < 2; ++s2) {                                        \
        bf16x8 kf = (h == 0) ? (s2 == 0 ? K0 : K1) : (s2 == 0 ? K2 : K3);     \
        f32x4 Sv = __builtin_amdgcn_mfma_f32_16x16x32_bf16(kf, qfrag, zero,   \
                                                           0, 0, 0);          \
        S[s2] = Sv;                                                           \
        float m = fmaxf(fmaxf(Sv[0], Sv[1]), fmaxf(Sv[2], Sv[3]));            \
        ok &= (m <= thr_all);                                                 \
      }                                                                       \
      if (__all((int)ok)) {                                                   \
        ++nclip;                                                              \
        const float vsA = h ? V1 : V0;                                        \
        const float vsB = h ? V3 : V2;                                        \
        _Pragma("unroll")                                                     \
        for (int r = 0; r < 4; ++r) {                                         \
          accO0[r] = fmaf(wrow[r], vsA, accO0[r]);                            \
          accO1[r] = fmaf(wrow[r], vsB, accO1[r]);                            \
        }                                                                     \
      } else {                                                                \
        _Pragma("unroll")                                                     \
        for (int s2 = 0; s2 < 2; ++s2) {                                      \
          const int sub = h * 2 + s2;                                         \
          const int tk = _t0 + sub * 16 + lg * 4;                             \
          f32x4 Sv = S[s2];                                                   \
          float w[4];                                                         \
          _Pragma("unroll")                                                   \
          for (int r = 0; r < 4; ++r) {                                       \
            float4 T = Tk[tk + r];                                            \
            float qk2 = Sv[r] + Sv[r];                                        \
            float u = (qq + T.x) - qk2;                                       \
            float d = fmaf(qq, T.x, 1.0f) - qk2;                              \
            float p = fmaxf(u * d, 0.0f);                                     \
            float sq = sqrtf(p);                                              \
            float m2 = fmaf(2.0f, sq, u + d);                                 \
            float e = fmaf(-ALPHA, fast_log2(m2), T.z);                       \
            e = fmaxf(e, eminRow);                                            \
            w[r] = fast_exp2(e);                                              \
          }                                                                   \
          den += (w[0] + w[1]) + (w[2] + w[3]);                               \
          union { __bf16 hh[4]; uint2 u2; } pk;                               \
          pk.hh[0] = (__bf16)w[0]; pk.hh[1] = (__bf16)w[1];                   \
          pk.hh[2] = (__bf16)w[2]; pk.hh[3] = (__bf16)w[3];                   \
          *(uint2*)&Pw[l15 * 72 + sub * 16 + lg * 4] = pk.u2;                 \
        }                                                                     \
        bf16x8 pfrag = *(const bf16x8*)&Pw[l15 * 72 + h * 32 + lg * 8];       \
        bf16x8 v0 = *(const bf16x8*)(Vbase + (size_t)l15 * 2048 + _t0 +       \
                                     h * 32 + lg * 8);                        \
        bf16x8 v1 = *(const bf16x8*)(Vbase + (size_t)(16 + l15) * 2048 +      \
                                     _t0 + h * 32 + lg * 8);                  \
        accO0 = __builtin_amdgcn_mfma_f32_16x16x32_bf16(pfrag, v0, accO0,     \
                                                        0, 0, 0);             \
        accO1 = __builtin_amdgcn_mfma_f32_16x16x32_bf16(pfrag, v1, accO1,     \
                                                        0, 0, 0);             \
      }                                                                       \
    }                                                                         \
    __builtin_amdgcn_s_setprio(0);                                            \
  }

  LOAD_SET(kfA0, kfA1, kfA2, kfA3, vA0, vA1, vA2, vA3,
           tbeg + ((stag & 7) << 6));

#pragma unroll
  for (int i = 0; i < 8; ++i) {
    const int tcur = tbeg + (((i + stag) & 7) << 6);
    const int tnxt = tbeg + (((i + 1 + stag) & 7) << 6);
    if ((i & 1) == 0) {
      if (i < 7) LOAD_SET(kfB0, kfB1, kfB2, kfB3, vB0, vB1, vB2, vB3, tnxt);
      COMPUTE_SET(kfA0, kfA1, kfA2, kfA3, vA0, vA1, vA2, vA3, tcur);
    } else {
      if (i < 7) LOAD_SET(kfA0, kfA1, kfA2, kfA3, vA0, vA1, vA2, vA3, tnxt);
      COMPUTE_SET(kfB0, kfB1, kfB2, kfB3, vB0, vB1, vB2, vB3, tcur);
    }
  }
#undef LOAD_SET
#undef COMPUTE_SET

  den = fmaf(8.0f * wclipf, (float)nclip, den);
  den += __shfl_xor(den, 16);
  den += __shfl_xor(den, 32);
  size_t pbase = ((size_t)tc * 16 + bh) * 2048;
  if (lg == 0) PD[pbase + s0 + l15] = den;
#pragma unroll
  for (int r = 0; r < 4; ++r) {
    int sl = lg * 4 + r;
    size_t row = (pbase + s0 + sl) * 32;
    PNb[row + l15]      = (__bf16)accO0[r];
    PNb[row + 16 + l15] = (__bf16)accO1[r];
  }
}

// ---------------------------------------------------------------------------
// Sum the 4 t-chunk bf16 partials, normalize, write AO as bf16 (h, l) pair.
__global__ __launch_bounds__(256)
void combine4(const __bf16* __restrict__ PNb, const float* __restrict__ PD,
              __bf16* __restrict__ AOh, __bf16* __restrict__ AOl) {
  int idx = blockIdx.x * 256 + threadIdx.x;   // 0..32767 = (bh, s)
  int bh = idx >> 11, s = idx & 2047;
  int b = bh >> 3, h = bh & 7;
  float den = 0.0f;
#pragma unroll
  for (int c = 0; c < 4; ++c) den += PD[((size_t)c * 16 + bh) * 2048 + s];
  float r = 1.0f / den;
  size_t ob = ((size_t)b * 2048 + s) * 256 + h * 32;
#pragma unroll
  for (int i = 0; i < 4; ++i) {               // 8 dh per iter
    float acc8[8] = {};
#pragma unroll
    for (int c = 0; c < 4; ++c) {
      bf16x8 v = *(const bf16x8*)&PNb[((((size_t)c * 16 + bh) * 2048 + s) * 32) + i * 8];
#pragma unroll
      for (int j = 0; j < 8; ++j) acc8[j] += (float)v[j];
    }
    union { __bf16 h8[8]; uint4 u; } ph, pl;
#pragma unroll
    for (int j = 0; j < 8; ++j) {
      float val = acc8[j] * r;
      __bf16 hb = (__bf16)val;
      ph.h8[j] = hb;
      pl.h8[j] = (__bf16)(val - (float)hb);
    }
    *(uint4*)(AOh + ob + i * 8) = ph.u;
    *(uint4*)(AOl + ob + i * 8) = pl.u;
  }
}

// ---------------------------------------------------------------------------
// Output projection, split-bf16 MFMA: out = AO @ Wcomb^T + bcomb. Grid (64,4).
__global__ __launch_bounds__(256)
void gemm_out_mfma(const __bf16* __restrict__ aoh, const __bf16* __restrict__ aol,
                   const __bf16* __restrict__ Wch, const __bf16* __restrict__ Wcl,
                   const float* __restrict__ bcomb, float* __restrict__ out) {
  const int tid = threadIdx.x, w = tid >> 6, lane = tid & 63;
  const int l15 = lane & 15, lg = lane >> 4;
  const int m0 = blockIdx.x * 64, n0 = blockIdx.y * 64;
  const int arow = m0 + w * 16 + l15;
  const __bf16* axh = aoh + (size_t)arow * 256 + lg * 8;
  const __bf16* axl = aol + (size_t)arow * 256 + lg * 8;
  f32x4 acc0 = {0,0,0,0}, acc1 = {0,0,0,0}, acc2 = {0,0,0,0}, acc3 = {0,0,0,0};
#pragma unroll
  for (int k0 = 0; k0 < 256; k0 += 32) {
    bf16x8 ah = *(const bf16x8*)(axh + k0);
    bf16x8 al = *(const bf16x8*)(axl + k0);
#pragma unroll
    for (int g = 0; g < 4; ++g) {
      const size_t br = (size_t)(n0 + g * 16 + l15) * 256 + lg * 8 + k0;
      bf16x8 bh = *(const bf16x8*)(Wch + br);
      bf16x8 bl = *(const bf16x8*)(Wcl + br);
      f32x4& acc = g == 0 ? acc0 : (g == 1 ? acc1 : (g == 2 ? acc2 : acc3));
      acc = __builtin_amdgcn_mfma_f32_16x16x32_bf16(ah, bh, acc, 0, 0, 0);
      acc = __builtin_amdgcn_mfma_f32_16x16x32_bf16(al, bh, acc, 0, 0, 0);
      acc = __builtin_amdgcn_mfma_f32_16x16x32_bf16(ah, bl, acc, 0, 0, 0);
    }
  }
#pragma unroll
  for (int g = 0; g < 4; ++g) {
    const f32x4& acc = g == 0 ? acc0 : (g == 1 ? acc1 : (g == 2 ? acc2 : acc3));
    int n = n0 + g * 16 + l15;
    float bval = bcomb[n];
#pragma unroll
    for (int r = 0; r < 4; ++r) {
      int m = m0 + w * 16 + lg * 4 + r;
      out[(size_t)m * 256 + n] = acc[r] + bval;
    }
  }
}

// ---------------------------------------------------------------------------
extern "C" void kernel_launch(void* const* d_in, const int* in_sizes, int n_in,
                              void* d_out, int out_size, void* d_ws, size_t ws_size,
                              hipStream_t stream) {
  const float* x   = (const float*)d_in[0];
  const float* Wq  = (const float*)d_in[1];
  const float* bq  = (const float*)d_in[2];
  const float* Wk  = (const float*)d_in[3];
  const float* bk  = (const float*)d_in[4];
  const float* Wv  = (const float*)d_in[5];
  const float* bv  = (const float*)d_in[6];
  const float* Wo  = (const float*)d_in[7];
  const float* bo  = (const float*)d_in[8];
  const float* Wfc = (const float*)d_in[9];
  const float* bfc = (const float*)d_in[10];

  float* ws = (float*)d_ws;
  // Workspace layout (float offsets); ~42.5 MB total.
  float* Vb  = ws + (2 << 20);                          // 1M
  __bf16* Qbf = (__bf16*)(ws + (3 << 20));              // 1M bf16
  __bf16* Kbf = (__bf16*)(ws + (3 << 20) + (1 << 19));  // 1M bf16
  __bf16* Vtb = (__bf16*)(ws + (4 << 20));              // 1M bf16
  float4* qtab4 = (float4*)(ws + (4 << 20) + (1 << 19));             // 128K f
  float4* ktab4 = (float4*)(ws + (4 << 20) + (1 << 19) + (1 << 17)); // 128K f
  float*  Vsum  = ws + (4 << 20) + (1 << 19) + (2 << 17);            // 32K f
  __bf16* Wch   = (__bf16*)(Vsum + (1 << 15));          // 64K bf16 (32K f)
  __bf16* Wcl   = Wch + 65536;                          // 64K bf16
  float*  bcomb = Vsum + (1 << 15) + (1 << 16);         // 256
  float2* Kred  = (float2*)(bcomb + 256);               // 512 float2 (1K f)
  __bf16* xh = (__bf16*)(ws + (5 << 20));               // 1M bf16
  __bf16* xl = (__bf16*)(ws + (5 << 20) + (1 << 19));   // 1M bf16
  __bf16* Wsplit = (__bf16*)(ws + (6 << 20));           // 393216 bf16
  __bf16* PNb = (__bf16*)(ws + (6 << 20) + (1 << 18));  // 4M bf16 (2M f)
  float* PD = ws + (6 << 20) + (1 << 18) + (2 << 20);   // 128K
  __bf16* AOh = (__bf16*)ws;                            // reuse slab 0
  __bf16* AOl = (__bf16*)(ws + (1 << 19));              // reuse slab 0

  dim3 blk(256);
  k1_misc<<<dim3(640), blk, 0, stream>>>(x, Wq, Wk, Wv, Wfc, Wo, bo, bfc,
                                         xh, xl, Wsplit, Wch, Wcl, bcomb);
  gemm_qkv_mfma<<<dim3(64, 12), blk, 0, stream>>>(xh, xl, Wsplit, bq, bk, bv,
                                                  Qbf, Kbf, Vb, qtab4, ktab4,
                                                  Kred);
  k3v<<<dim3(640), blk, 0, stream>>>(Vb, Vtb, Vsum);
  attn_mfma<<<dim3(32, 4, 16), blk, 0, stream>>>(Qbf, Kbf, Vtb, qtab4, ktab4,
                                                 Vsum, Kred, PNb, PD);
  combine4<<<dim3(128), blk, 0, stream>>>(PNb, PD, AOh, AOl);
  gemm_out_mfma<<<dim3(64, 4), blk, 0, stream>>>(AOh, AOl, Wch, Wcl, bcomb,
                                                 (float*)d_out);
}

// Round 16
// 101.581 us; speedup vs baseline: 1.0842x; 1.0415x over previous
//
#include <hip/hip_runtime.h>
#include <cstdint>
#include <cstddef>

// Poincare-ball (hyperbolic) attention block. B=2, S=2048, D=256, H=8, dh=32, c=1.
//
// Round 16 = round 15 with the V-epilogue bugs fixed:
//  - V^T write now covers all 16 bf16 per thread (two uint4 stores).
//  - t index uses (m0 & 2047)  [batch-1 blocks overflowed the t dim].
//  - Vsum t32 index uses ((m0 & 2047) >> 5)  [was stomping Wch/Wcl -> NaN].
// Round-15 changes retained: attn/gemm_qkv __launch_bounds__(256,4),
// gemm_out (256,1), k3v eliminated (V^T + Vsum fused into gemm_qkv).

#define ALPHA 0.17677669529663687f   // 1/sqrt(32)
#define EMIN  -3.1129694f            // -ALPHA * log2((2-1e-5)/1e-5)  (clip)
#define CHI   1.95e-5f               // conservative 1-(1-1e-5)^2
#define NEG_INV_2CHI -25641.026f     // -1/(2*CHI)
#define TWOLOG2E 2.8853900817779268f // 2*log2(e)

typedef __bf16 bf16x8 __attribute__((ext_vector_type(8)));
typedef float  f32x4  __attribute__((ext_vector_type(4)));

__device__ __forceinline__ float fast_log2(float x) { return __builtin_amdgcn_logf(x); }
__device__ __forceinline__ float fast_exp2(float x) { return __builtin_amdgcn_exp2f(x); }

// ---------------------------------------------------------------------------
// K1: fused {Wcomb = Wfc@Wo (blocks 0-15)} {bcomb = Wfc@bo+bfc (16-31)}
//     {fp32->bf16 h/l splits of x, Wq, Wk, Wv (32-639)}.
__global__ __launch_bounds__(256)
void k1_misc(const float* __restrict__ x,   const float* __restrict__ Wq,
             const float* __restrict__ Wk,  const float* __restrict__ Wv,
             const float* __restrict__ Wfc, const float* __restrict__ Wo,
             const float* __restrict__ bo,  const float* __restrict__ bfc,
             __bf16* __restrict__ xh, __bf16* __restrict__ xl,
             __bf16* __restrict__ Ws, __bf16* __restrict__ Wch,
             __bf16* __restrict__ Wcl, float* __restrict__ bcomb) {
  __shared__ float sh[2 * 32 * 68];
  const int bx = blockIdx.x, tid = threadIdx.x;
  if (bx < 16) {
    float (*AsT)[68] = (float(*)[68])sh;
    float (*Bs)[68]  = (float(*)[68])(sh + 32 * 68);
    const int ty = tid >> 4, tx = tid & 15;
    const int m0 = (bx >> 2) * 64, n0 = (bx & 3) * 64;
    float acc[4][4] = {};
    for (int k0 = 0; k0 < 256; k0 += 32) {
#pragma unroll
      for (int jj = 0; jj < 2; ++jj) {
        int j = tid * 2 + jj;
        {
          int r = j >> 3, c4 = (j & 7) << 2;
          float4 av = *(const float4*)&Wfc[(size_t)(m0 + r) * 256 + k0 + c4];
          AsT[c4 + 0][r] = av.x; AsT[c4 + 1][r] = av.y;
          AsT[c4 + 2][r] = av.z; AsT[c4 + 3][r] = av.w;
        }
        {
          int r = j >> 4, c4 = (j & 15) << 2;
          *(float4*)&Bs[r][c4] = *(const float4*)&Wo[(size_t)(k0 + r) * 256 + n0 + c4];
        }
      }
      __syncthreads();
#pragma unroll
      for (int kk = 0; kk < 32; ++kk) {
        float4 a = *(const float4*)&AsT[kk][ty * 4];
        float4 b = *(const float4*)&Bs[kk][tx * 4];
        float av[4] = {a.x, a.y, a.z, a.w};
        float bv[4] = {b.x, b.y, b.z, b.w};
#pragma unroll
        for (int i = 0; i < 4; ++i)
#pragma unroll
          for (int j2 = 0; j2 < 4; ++j2)
            acc[i][j2] = fmaf(av[i], bv[j2], acc[i][j2]);
      }
      __syncthreads();
    }
#pragma unroll
    for (int i = 0; i < 4; ++i) {
      union { __bf16 h[4]; uint2 u; } ph, pl;
#pragma unroll
      for (int j = 0; j < 4; ++j) {
        __bf16 hb = (__bf16)acc[i][j];
        ph.h[j] = hb;
        pl.h[j] = (__bf16)(acc[i][j] - (float)hb);
      }
      size_t off = (size_t)(m0 + ty * 4 + i) * 256 + n0 + tx * 4;
      *(uint2*)(Wch + off) = ph.u;
      *(uint2*)(Wcl + off) = pl.u;
    }
  } else if (bx < 32) {
    float* red = sh;
    int r = tid >> 4, c = tid & 15;
    int row = (bx - 16) * 16 + r;
    float s = 0.0f;
    for (int k = c; k < 256; k += 16) s = fmaf(Wfc[(size_t)row * 256 + k], bo[k], s);
    red[tid] = s;
    __syncthreads();
    if (c == 0) {
      float t = 0.0f;
#pragma unroll
      for (int i = 0; i < 16; ++i) t += red[r * 16 + i];
      bcomb[row] = t + bfc[row];
    }
  } else {
    int g = (bx - 32) * 256 + tid;
    const float* src;
    __bf16 *dh, *dl;
    if (g < 131072) {
      src = x + (size_t)g * 8; dh = xh + (size_t)g * 8; dl = xl + (size_t)g * 8;
    } else {
      int e = g - 131072;
      int wsel = e >> 13;
      int inner = (e & 8191) * 8;
      src = (wsel == 0 ? Wq : (wsel == 1 ? Wk : Wv)) + inner;
      dh = Ws + wsel * 131072 + inner;
      dl = Ws + wsel * 131072 + 65536 + inner;
    }
    union { __bf16 h[8]; uint4 u; } ph, pl;
#pragma unroll
    for (int i = 0; i < 2; ++i) {
      float4 v = *(const float4*)(src + i * 4);
      float vv[4] = {v.x, v.y, v.z, v.w};
#pragma unroll
      for (int j = 0; j < 4; ++j) {
        __bf16 hb = (__bf16)vv[j];
        ph.h[i * 4 + j] = hb;
        pl.h[i * 4 + j] = (__bf16)(vv[j] - (float)hb);
      }
    }
    *(uint4*)dh = ph.u;
    *(uint4*)dl = pl.u;
  }
}

// ---------------------------------------------------------------------------
// Fused QKV projection + expmap prep + V^T/Vsum, split-bf16 MFMA.
// Grid (64, 12), 4 waves.
__global__ __launch_bounds__(256, 4)
void gemm_qkv_mfma(const __bf16* __restrict__ xh, const __bf16* __restrict__ xl,
                   const __bf16* __restrict__ Ws,
                   const float* __restrict__ bq, const float* __restrict__ bk,
                   const float* __restrict__ bv,
                   __bf16* __restrict__ Qbf, __bf16* __restrict__ Kbf,
                   __bf16* __restrict__ Vt, float* __restrict__ Vsum,
                   float4* __restrict__ qtab4, float4* __restrict__ ktab4,
                   float2* __restrict__ Kred) {
  __shared__ float4 kredsh[4];
  __shared__ __bf16 sh_vt[64][64];       // 8 KB (V path)
  __shared__ float  vsred[4][4][64];     // 4 KB (V path)
  const int tid = threadIdx.x, w = tid >> 6, lane = tid & 63;
  const int l15 = lane & 15, lg = lane >> 4;
  const int m0 = blockIdx.x * 64, nb = blockIdx.y;
  const int wsel = nb >> 2;
  const int n256b = (nb & 3) * 64;
  const __bf16* Wh = Ws + wsel * 131072;
  const __bf16* Wl = Wh + 65536;
  const int arow = m0 + w * 16 + l15;
  const __bf16* axh = xh + (size_t)arow * 256 + lg * 8;
  const __bf16* axl = xl + (size_t)arow * 256 + lg * 8;
  f32x4 acc0 = {0,0,0,0}, acc1 = {0,0,0,0}, acc2 = {0,0,0,0}, acc3 = {0,0,0,0};
#pragma unroll
  for (int k0 = 0; k0 < 256; k0 += 32) {
    bf16x8 ah = *(const bf16x8*)(axh + k0);
    bf16x8 al = *(const bf16x8*)(axl + k0);
#pragma unroll
    for (int g = 0; g < 4; ++g) {
      const size_t br = (size_t)(n256b + g * 16 + l15) * 256 + lg * 8 + k0;
      bf16x8 bh = *(const bf16x8*)(Wh + br);
      bf16x8 bl = *(const bf16x8*)(Wl + br);
      f32x4& acc = g == 0 ? acc0 : (g == 1 ? acc1 : (g == 2 ? acc2 : acc3));
      acc = __builtin_amdgcn_mfma_f32_16x16x32_bf16(ah, bh, acc, 0, 0, 0);
      acc = __builtin_amdgcn_mfma_f32_16x16x32_bf16(al, bh, acc, 0, 0, 0);
      acc = __builtin_amdgcn_mfma_f32_16x16x32_bf16(ah, bl, acc, 0, 0, 0);
    }
  }
  const float* bias = wsel == 0 ? bq : (wsel == 1 ? bk : bv);
  const int b = m0 >> 11;                    // block-uniform
  const int headA = n256b >> 5;              // {0,2,4,6}
  const int sLoc = m0 & 2047;                // t/s offset within the batch

  if (wsel == 2) {
    // ---- V: stage fp32+bias into LDS transpose + per-lane 4-t sums ----
#pragma unroll
    for (int g = 0; g < 4; ++g) {
      const f32x4& acc = g == 0 ? acc0 : (g == 1 ? acc1 : (g == 2 ? acc2 : acc3));
      int col = g * 16 + l15;
      float bval = bias[n256b + col];
      float p = 0.0f;
#pragma unroll
      for (int r = 0; r < 4; ++r) {
        float v = acc[r] + bval;
        sh_vt[col][w * 16 + lg * 4 + r] = (__bf16)v;
        p += v;
      }
      vsred[w][lg][col] = p;
    }
    __syncthreads();
    {   // coalesced V^T write: 256 threads x 32B (two uint4 each, 16 bf16)
      int col = tid >> 2, sg = tid & 3;
      int bh = (b << 3) + headA + (col >> 5);
      int d = col & 31;
      uint4 v0 = *(const uint4*)&sh_vt[col][sg * 16];
      uint4 v1 = *(const uint4*)&sh_vt[col][sg * 16 + 8];
      __bf16* dstp = Vt + ((size_t)bh * 32 + d) * 2048 + sLoc + sg * 16;
      *(uint4*)dstp = v0;
      *(uint4*)(dstp + 8) = v1;
    }
    if (tid < 128) {  // Vsum32: reduce 8 partials per (t32, col)
      int tgrp = tid >> 6, col = tid & 63;
      float s = 0.0f;
#pragma unroll
      for (int w2 = 0; w2 < 2; ++w2)
#pragma unroll
        for (int l2 = 0; l2 < 4; ++l2)
          s += vsred[tgrp * 2 + w2][l2][col];
      int bh = (b << 3) + headA + (col >> 5);
      int d = col & 31;
      Vsum[((size_t)bh * 64 + (sLoc >> 5) + tgrp) * 32 + d] = s;
    }
    return;
  }

  // ---- Q/K: fused expmap prep ----
  const float bv0 = bias[n256b + 0 * 16 + l15];
  const float bv1 = bias[n256b + 1 * 16 + l15];
  const float bv2 = bias[n256b + 2 * 16 + l15];
  const float bv3 = bias[n256b + 3 * 16 + l15];
  float ssA[4], ssB[4];
#pragma unroll
  for (int r = 0; r < 4; ++r) {
    acc0[r] += bv0; acc1[r] += bv1; acc2[r] += bv2; acc3[r] += bv3;
    ssA[r] = acc0[r] * acc0[r] + acc1[r] * acc1[r];
    ssB[r] = acc2[r] * acc2[r] + acc3[r] * acc3[r];
  }
#pragma unroll
  for (int mk = 1; mk < 16; mk <<= 1) {
#pragma unroll
    for (int r = 0; r < 4; ++r) {
      ssA[r] += __shfl_xor(ssA[r], mk);
      ssB[r] += __shfl_xor(ssB[r], mk);
    }
  }
  float scA[4], qqA[4], BvA[4], lgA[4];
  float scB[4], qqB[4], BvB[4], lgB_[4];
#pragma unroll
  for (int r = 0; r < 4; ++r) {
    {
      float ss = fmaxf(ssA[r], 1e-12f);
      float xv = sqrtf(ss);
      float ex = fast_exp2(-TWOLOG2E * xv);
      float opex = 1.0f + ex;
      float th = (1.0f - ex) / opex;
      scA[r] = th / xv;
      qqA[r] = th * th;
      BvA[r] = 4.0f * ex / (opex * opex);
      lgA[r] = 2.0f - TWOLOG2E * xv - 2.0f * fast_log2(opex);
    }
    {
      float ss = fmaxf(ssB[r], 1e-12f);
      float xv = sqrtf(ss);
      float ex = fast_exp2(-TWOLOG2E * xv);
      float opex = 1.0f + ex;
      float th = (1.0f - ex) / opex;
      scB[r] = th / xv;
      qqB[r] = th * th;
      BvB[r] = 4.0f * ex / (opex * opex);
      lgB_[r] = 2.0f - TWOLOG2E * xv - 2.0f * fast_log2(opex);
    }
  }
  __bf16* dst = wsel == 0 ? Qbf : Kbf;
  float4* tab = wsel == 0 ? qtab4 : ktab4;
  const int headB = headA + 1;
  const int bhA = (b << 3) + headA, bhB = (b << 3) + headB;
  const int sbase = sLoc + w * 16 + lg * 4;
#pragma unroll
  for (int r = 0; r < 4; ++r) {
    int s = sbase + r;
    size_t baseA = ((size_t)bhA * 2048 + s) * 32;
    size_t baseB = ((size_t)bhB * 2048 + s) * 32;
    dst[baseA + l15]      = (__bf16)(acc0[r] * scA[r]);
    dst[baseA + 16 + l15] = (__bf16)(acc1[r] * scA[r]);
    dst[baseB + l15]      = (__bf16)(acc2[r] * scB[r]);
    dst[baseB + 16 + l15] = (__bf16)(acc3[r] * scB[r]);
    if (l15 == 0) {
      if (wsel == 0) {
        tab[(size_t)bhA * 2048 + s] = float4{qqA[r], ALPHA * lgA[r], BvA[r], 0.0f};
        tab[(size_t)bhB * 2048 + s] = float4{qqB[r], ALPHA * lgB_[r], BvB[r], 0.0f};
      } else {
        tab[(size_t)bhA * 2048 + s] = float4{qqA[r], BvA[r], ALPHA * lgA[r], 0.0f};
        tab[(size_t)bhB * 2048 + s] = float4{qqB[r], BvB[r], ALPHA * lgB_[r], 0.0f};
      }
    }
  }
  if (wsel == 1) {
    float mnA = fminf(fminf(qqA[0], qqA[1]), fminf(qqA[2], qqA[3]));
    float mxA = fmaxf(fmaxf(BvA[0], BvA[1]), fmaxf(BvA[2], BvA[3]));
    float mnB = fminf(fminf(qqB[0], qqB[1]), fminf(qqB[2], qqB[3]));
    float mxB = fmaxf(fmaxf(BvB[0], BvB[1]), fmaxf(BvB[2], BvB[3]));
    mnA = fminf(mnA, __shfl_xor(mnA, 16)); mnA = fminf(mnA, __shfl_xor(mnA, 32));
    mxA = fmaxf(mxA, __shfl_xor(mxA, 16)); mxA = fmaxf(mxA, __shfl_xor(mxA, 32));
    mnB = fminf(mnB, __shfl_xor(mnB, 16)); mnB = fminf(mnB, __shfl_xor(mnB, 32));
    mxB = fmaxf(mxB, __shfl_xor(mxB, 16)); mxB = fmaxf(mxB, __shfl_xor(mxB, 32));
    if (lane == 0) kredsh[w] = float4{mnA, mxA, mnB, mxB};
    __syncthreads();
    if (tid == 0) {
      float4 a = kredsh[0], b4 = kredsh[1], c4 = kredsh[2], d4 = kredsh[3];
      float MnA = fminf(fminf(a.x, b4.x), fminf(c4.x, d4.x));
      float MxA = fmaxf(fmaxf(a.y, b4.y), fmaxf(c4.y, d4.y));
      float MnB = fminf(fminf(a.z, b4.z), fminf(c4.z, d4.z));
      float MxB = fmaxf(fmaxf(a.w, b4.w), fmaxf(c4.w, d4.w));
      int bx31 = blockIdx.x & 31;
      Kred[bhA * 32 + bx31] = float2{MnA, MxA};
      Kred[bhB * 32 + bx31] = float2{MnB, MxB};
    }
  }
}

// ---------------------------------------------------------------------------
// Flash attention (round-13 pipeline; 128-VGPR budget). Grid (32, 4, 16).
__global__ __launch_bounds__(256, 4)
void attn_mfma(const __bf16* __restrict__ Qbf, const __bf16* __restrict__ Kbf,
               const __bf16* __restrict__ Vt,  const float4* __restrict__ qtab4,
               const float4* __restrict__ ktab4, const float* __restrict__ Vsum,
               const float2* __restrict__ Kred,
               __bf16* __restrict__ PNb, float* __restrict__ PD) {
  __shared__ __bf16 Pt[4][16][72];   // rare-path per-wave P^T (wave-private)
  const int tid = threadIdx.x;
  const int wid = tid >> 6, lane = tid & 63;
  const int l15 = lane & 15, lg = lane >> 4;
  const int tc = blockIdx.y, bh = blockIdx.z;
  const int sblk = blockIdx.x;
  const int s0 = sblk * 64 + wid * 16;

  bf16x8 qfrag = *(const bf16x8*)(Qbf + ((size_t)bh * 2048 + s0 + l15) * 32 + lg * 8);
  float4 qt = qtab4[bh * 2048 + s0 + l15];
  const float qq = qt.x, Bq = qt.z;
  const float eminRow = EMIN - qt.y;
  const float wclipf = (float)(__bf16)fast_exp2(eminRow);   // bf16-quantized
  float wrow[4];
#pragma unroll
  for (int r = 0; r < 4; ++r)
    wrow[r] = (float)(__bf16)fast_exp2(EMIN - qtab4[bh * 2048 + s0 + lg * 4 + r].y);

  float kkmin = 1.0f, bkmax = 0.0f;
#pragma unroll
  for (int j = 0; j < 32; ++j) {
    float2 kr = Kred[bh * 32 + j];
    kkmin = fminf(kkmin, kr.x);
    bkmax = fmaxf(bkmax, kr.y);
  }
  const float thr_all = fmaf(0.5f * qq, kkmin,
                             fmaf(Bq * NEG_INV_2CHI, bkmax, 0.5f));

  const __bf16* Kbase = Kbf + ((size_t)bh << 16);
  const __bf16* Vbase = Vt + ((size_t)bh << 16);
  const float4* Tk = ktab4 + bh * 2048;
  const float*  VsBase = Vsum + (size_t)bh * 64 * 32;
  __bf16* Pw = &Pt[wid][0][0];

  f32x4 accO0 = {0.f, 0.f, 0.f, 0.f};
  f32x4 accO1 = {0.f, 0.f, 0.f, 0.f};
  float den = 0.0f;
  int nclip = 0;
  const f32x4 zero = {0.f, 0.f, 0.f, 0.f};
  const int tbeg = tc * 512;
  const int stag = sblk & 7;

  bf16x8 kfA0, kfA1, kfA2, kfA3, kfB0, kfB1, kfB2, kfB3;
  float vA0, vA1, vA2, vA3, vB0, vB1, vB2, vB3;

#define LOAD_SET(K0, K1, K2, K3, V0, V1, V2, V3, T0)                          \
  {                                                                           \
    const int _t = (T0);                                                      \
    K0 = *(const bf16x8*)(Kbase + (size_t)(_t + 0 * 16 + l15) * 32 + lg * 8); \
    K1 = *(const bf16x8*)(Kbase + (size_t)(_t + 1 * 16 + l15) * 32 + lg * 8); \
    K2 = *(const bf16x8*)(Kbase + (size_t)(_t + 2 * 16 + l15) * 32 + lg * 8); \
    K3 = *(const bf16x8*)(Kbase + (size_t)(_t + 3 * 16 + l15) * 32 + lg * 8); \
    const int _ti = _t >> 5;                                                  \
    V0 = VsBase[_ti * 32 + l15];                                              \
    V1 = VsBase[(_ti + 1) * 32 + l15];                                        \
    V2 = VsBase[_ti * 32 + 16 + l15];                                         \
    V3 = VsBase[(_ti + 1) * 32 + 16 + l15];                                   \
  }

#define COMPUTE_SET(K0, K1, K2, K3, V0, V1, V2, V3, T0)                       \
  {                                                                           \
    const int _t0 = (T0);                                                     \
    __builtin_amdgcn_s_setprio(1);                                            \
    _Pragma("unroll")                                                         \
    for (int h = 0; h < 2; ++h) {                                             \
      f32x4 S[2];                                                             \
      bool ok = true;                                                         \
      _Pragma("unroll")                                                       \
      for (int s2 = 0; s2 < 2; ++s2) {                                        \
        bf16x8 kf = (h == 0) ? (s2 == 0 ? K0 : K1) : (s2 == 0 ? K2 : K3);     \
        f32x4 Sv = __builtin_amdgcn_mfma_f32_16x16x32_bf16(kf, qfrag, zero,   \
                                                           0, 0, 0);          \
        S[s2] = Sv;                                                           \
        float m = fmaxf(fmaxf(Sv[0], Sv[1]), fmaxf(Sv[2], Sv[3]));            \
        ok &= (m <= thr_all);                                                 \
      }                                                                       \
      if (__all((int)ok)) {                                                   \
        ++nclip;                                                              \
        const float vsA = h ? V1 : V0;                                        \
        const float vsB = h ? V3 : V2;                                        \
        _Pragma("unroll")                                                     \
        for (int r = 0; r < 4; ++r) {                                         \
          accO0[r] = fmaf(wrow[r], vsA, accO0[r]);                            \
          accO1[r] = fmaf(wrow[r], vsB, accO1[r]);                            \
        }                                                                     \
      } else {                                                                \
        _Pragma("unroll")                                                     \
        for (int s2 = 0; s2 < 2; ++s2) {                                      \
          const int sub = h * 2 + s2;                                         \
          const int tk = _t0 + sub * 16 + lg * 4;                             \
          f32x4 Sv = S[s2];                                                   \
          float w[4];                                                         \
          _Pragma("unroll")                                                   \
          for (int r = 0; r < 4; ++r) {                                       \
            float4 T = Tk[tk + r];                                            \
            float qk2 = Sv[r] + Sv[r];                                        \
            float u = (qq + T.x) - qk2;                                       \
            float d = fmaf(qq, T.x, 1.0f) - qk2;                              \
            float p = fmaxf(u * d, 0.0f);                                     \
            float sq = sqrtf(p);                                              \
            float m2 = fmaf(2.0f, sq, u + d);                                 \
            float e = fmaf(-ALPHA, fast_log2(m2), T.z);                       \
            e = fmaxf(e, eminRow);                                            \
            w[r] = fast_exp2(e);                                              \
          }                                                                   \
          den += (w[0] + w[1]) + (w[2] + w[3]);                               \
          union { __bf16 hh[4]; uint2 u2; } pk;                               \
          pk.hh[0] = (__bf16)w[0]; pk.hh[1] = (__bf16)w[1];                   \
          pk.hh[2] = (__bf16)w[2]; pk.hh[3] = (__bf16)w[3];                   \
          *(uint2*)&Pw[l15 * 72 + sub * 16 + lg * 4] = pk.u2;                 \
        }                                                                     \
        bf16x8 pfrag = *(const bf16x8*)&Pw[l15 * 72 + h * 32 + lg * 8];       \
        bf16x8 v0 = *(const bf16x8*)(Vbase + (size_t)l15 * 2048 + _t0 +       \
                                     h * 32 + lg * 8);                        \
        bf16x8 v1 = *(const bf16x8*)(Vbase + (size_t)(16 + l15) * 2048 +      \
                                     _t0 + h * 32 + lg * 8);                  \
        accO0 = __builtin_amdgcn_mfma_f32_16x16x32_bf16(pfrag, v0, accO0,     \
                                                        0, 0, 0);             \
        accO1 = __builtin_amdgcn_mfma_f32_16x16x32_bf16(pfrag, v1, accO1,     \
                                                        0, 0, 0);             \
      }                                                                       \
    }                                                                         \
    __builtin_amdgcn_s_setprio(0);                                            \
  }

  LOAD_SET(kfA0, kfA1, kfA2, kfA3, vA0, vA1, vA2, vA3,
           tbeg + ((stag & 7) << 6));

#pragma unroll
  for (int i = 0; i < 8; ++i) {
    const int tcur = tbeg + (((i + stag) & 7) << 6);
    const int tnxt = tbeg + (((i + 1 + stag) & 7) << 6);
    if ((i & 1) == 0) {
      if (i < 7) LOAD_SET(kfB0, kfB1, kfB2, kfB3, vB0, vB1, vB2, vB3, tnxt);
      COMPUTE_SET(kfA0, kfA1, kfA2, kfA3, vA0, vA1, vA2, vA3, tcur);
    } else {
      if (i < 7) LOAD_SET(kfA0, kfA1, kfA2, kfA3, vA0, vA1, vA2, vA3, tnxt);
      COMPUTE_SET(kfB0, kfB1, kfB2, kfB3, vB0, vB1, vB2, vB3, tcur);
    }
  }
#undef LOAD_SET
#undef COMPUTE_SET

  den = fmaf(8.0f * wclipf, (float)nclip, den);
  den += __shfl_xor(den, 16);
  den += __shfl_xor(den, 32);
  size_t pbase = ((size_t)tc * 16 + bh) * 2048;
  if (lg == 0) PD[pbase + s0 + l15] = den;
#pragma unroll
  for (int r = 0; r < 4; ++r) {
    int sl = lg * 4 + r;
    size_t row = (pbase + s0 + sl) * 32;
    PNb[row + l15]      = (__bf16)accO0[r];
    PNb[row + 16 + l15] = (__bf16)accO1[r];
  }
}

// ---------------------------------------------------------------------------
// Sum the 4 t-chunk bf16 partials, normalize, write AO as bf16 (h, l) pair.
__global__ __launch_bounds__(256)
void combine4(const __bf16* __restrict__ PNb, const float* __restrict__ PD,
              __bf16* __restrict__ AOh, __bf16* __restrict__ AOl) {
  int idx = blockIdx.x * 256 + threadIdx.x;   // 0..32767 = (bh, s)
  int bh = idx >> 11, s = idx & 2047;
  int b = bh >> 3, h = bh & 7;
  float den = 0.0f;
#pragma unroll
  for (int c = 0; c < 4; ++c) den += PD[((size_t)c * 16 + bh) * 2048 + s];
  float r = 1.0f / den;
  size_t ob = ((size_t)b * 2048 + s) * 256 + h * 32;
#pragma unroll
  for (int i = 0; i < 4; ++i) {               // 8 dh per iter
    float acc8[8] = {};
#pragma unroll
    for (int c = 0; c < 4; ++c) {
      bf16x8 v = *(const bf16x8*)&PNb[((((size_t)c * 16 + bh) * 2048 + s) * 32) + i * 8];
#pragma unroll
      for (int j = 0; j < 8; ++j) acc8[j] += (float)v[j];
    }
    union { __bf16 h8[8]; uint4 u; } ph, pl;
#pragma unroll
    for (int j = 0; j < 8; ++j) {
      float val = acc8[j] * r;
      __bf16 hb = (__bf16)val;
      ph.h8[j] = hb;
      pl.h8[j] = (__bf16)(val - (float)hb);
    }
    *(uint4*)(AOh + ob + i * 8) = ph.u;
    *(uint4*)(AOl + ob + i * 8) = pl.u;
  }
}

// ---------------------------------------------------------------------------
// Output projection, split-bf16 MFMA: out = AO @ Wcomb^T + bcomb. Grid (64,4).
__global__ __launch_bounds__(256, 1)
void gemm_out_mfma(const __bf16* __restrict__ aoh, const __bf16* __restrict__ aol,
                   const __bf16* __restrict__ Wch, const __bf16* __restrict__ Wcl,
                   const float* __restrict__ bcomb, float* __restrict__ out) {
  const int tid = threadIdx.x, w = tid >> 6, lane = tid & 63;
  const int l15 = lane & 15, lg = lane >> 4;
  const int m0 = blockIdx.x * 64, n0 = blockIdx.y * 64;
  const int arow = m0 + w * 16 + l15;
  const __bf16* axh = aoh + (size_t)arow * 256 + lg * 8;
  const __bf16* axl = aol + (size_t)arow * 256 + lg * 8;
  f32x4 acc0 = {0,0,0,0}, acc1 = {0,0,0,0}, acc2 = {0,0,0,0}, acc3 = {0,0,0,0};
#pragma unroll
  for (int k0 = 0; k0 < 256; k0 += 32) {
    bf16x8 ah = *(const bf16x8*)(axh + k0);
    bf16x8 al = *(const bf16x8*)(axl + k0);
#pragma unroll
    for (int g = 0; g < 4; ++g) {
      const size_t br = (size_t)(n0 + g * 16 + l15) * 256 + lg * 8 + k0;
      bf16x8 bh = *(const bf16x8*)(Wch + br);
      bf16x8 bl = *(const bf16x8*)(Wcl + br);
      f32x4& acc = g == 0 ? acc0 : (g == 1 ? acc1 : (g == 2 ? acc2 : acc3));
      acc = __builtin_amdgcn_mfma_f32_16x16x32_bf16(ah, bh, acc, 0, 0, 0);
      acc = __builtin_amdgcn_mfma_f32_16x16x32_bf16(al, bh, acc, 0, 0, 0);
      acc = __builtin_amdgcn_mfma_f32_16x16x32_bf16(ah, bl, acc, 0, 0, 0);
    }
  }
#pragma unroll
  for (int g = 0; g < 4; ++g) {
    const f32x4& acc = g == 0 ? acc0 : (g == 1 ? acc1 : (g == 2 ? acc2 : acc3));
    int n = n0 + g * 16 + l15;
    float bval = bcomb[n];
#pragma unroll
    for (int r = 0; r < 4; ++r) {
      int m = m0 + w * 16 + lg * 4 + r;
      out[(size_t)m * 256 + n] = acc[r] + bval;
    }
  }
}

// ---------------------------------------------------------------------------
extern "C" void kernel_launch(void* const* d_in, const int* in_sizes, int n_in,
                              void* d_out, int out_size, void* d_ws, size_t ws_size,
                              hipStream_t stream) {
  const float* x   = (const float*)d_in[0];
  const float* Wq  = (const float*)d_in[1];
  const float* bq  = (const float*)d_in[2];
  const float* Wk  = (const float*)d_in[3];
  const float* bk  = (const float*)d_in[4];
  const float* Wv  = (const float*)d_in[5];
  const float* bv  = (const float*)d_in[6];
  const float* Wo  = (const float*)d_in[7];
  const float* bo  = (const float*)d_in[8];
  const float* Wfc = (const float*)d_in[9];
  const float* bfc = (const float*)d_in[10];

  float* ws = (float*)d_ws;
  // Workspace layout (float offsets); ~42.5 MB total.
  __bf16* Qbf = (__bf16*)(ws + (3 << 20));              // 1M bf16
  __bf16* Kbf = (__bf16*)(ws + (3 << 20) + (1 << 19));  // 1M bf16
  __bf16* Vtb = (__bf16*)(ws + (4 << 20));              // 1M bf16
  float4* qtab4 = (float4*)(ws + (4 << 20) + (1 << 19));             // 128K f
  float4* ktab4 = (float4*)(ws + (4 << 20) + (1 << 19) + (1 << 17)); // 128K f
  float*  Vsum  = ws + (4 << 20) + (1 << 19) + (2 << 17);            // 32K f
  __bf16* Wch   = (__bf16*)(Vsum + (1 << 15));          // 64K bf16 (32K f)
  __bf16* Wcl   = Wch + 65536;                          // 64K bf16
  float*  bcomb = Vsum + (1 << 15) + (1 << 16);         // 256
  float2* Kred  = (float2*)(bcomb + 256);               // 512 float2 (1K f)
  __bf16* xh = (__bf16*)(ws + (5 << 20));               // 1M bf16
  __bf16* xl = (__bf16*)(ws + (5 << 20) + (1 << 19));   // 1M bf16
  __bf16* Wsplit = (__bf16*)(ws + (6 << 20));           // 393216 bf16
  __bf16* PNb = (__bf16*)(ws + (6 << 20) + (1 << 18));  // 4M bf16 (2M f)
  float* PD = ws + (6 << 20) + (1 << 18) + (2 << 20);   // 128K
  __bf16* AOh = (__bf16*)ws;                            // reuse slab 0
  __bf16* AOl = (__bf16*)(ws + (1 << 19));              // reuse slab 0

  dim3 blk(256);
  k1_misc<<<dim3(640), blk, 0, stream>>>(x, Wq, Wk, Wv, Wfc, Wo, bo, bfc,
                                         xh, xl, Wsplit, Wch, Wcl, bcomb);
  gemm_qkv_mfma<<<dim3(64, 12), blk, 0, stream>>>(xh, xl, Wsplit, bq, bk, bv,
                                                  Qbf, Kbf, Vtb, Vsum,
                                                  qtab4, ktab4, Kred);
  attn_mfma<<<dim3(32, 4, 16), blk, 0, stream>>>(Qbf, Kbf, Vtb, qtab4, ktab4,
                                                 Vsum, Kred, PNb, PD);
  combine4<<<dim3(128), blk, 0, stream>>>(PNb, PD, AOh, AOl);
  gemm_out_mfma<<<dim3(64, 4), blk, 0, stream>>>(AOh, AOl, Wch, Wcl, bcomb,
                                                 (float*)d_out);
}

// Round 17
// 101.364 us; speedup vs baseline: 1.0865x; 1.0021x over previous
//
#include <hip/hip_runtime.h>
#include <cstdint>
#include <cstddef>

// Poincare-ball (hyperbolic) attention block. B=2, S=2048, D=256, H=8, dh=32, c=1.
//
// Round 17 (vs round 16): XCD-aware block swizzle on attn_mfma ONLY.
// Grid is 1-D (2048); wgid&7 = bh low bits -> all 128 blocks of one bh land
// on one XCD (round-robin dispatch), so per-XCD L2 working set drops from
// ~16 bh x 450 KB (7.2 MB, thrashing the 4 MB L2 -> every load at L3
// latency) to 2 bh x 450 KB (900 KB, L2-resident). Kernel math unchanged.

#define ALPHA 0.17677669529663687f   // 1/sqrt(32)
#define EMIN  -3.1129694f            // -ALPHA * log2((2-1e-5)/1e-5)  (clip)
#define CHI   1.95e-5f               // conservative 1-(1-1e-5)^2
#define NEG_INV_2CHI -25641.026f     // -1/(2*CHI)
#define TWOLOG2E 2.8853900817779268f // 2*log2(e)

typedef __bf16 bf16x8 __attribute__((ext_vector_type(8)));
typedef float  f32x4  __attribute__((ext_vector_type(4)));

__device__ __forceinline__ float fast_log2(float x) { return __builtin_amdgcn_logf(x); }
__device__ __forceinline__ float fast_exp2(float x) { return __builtin_amdgcn_exp2f(x); }

// ---------------------------------------------------------------------------
// K1: fused {Wcomb = Wfc@Wo (blocks 0-15)} {bcomb = Wfc@bo+bfc (16-31)}
//     {fp32->bf16 h/l splits of x, Wq, Wk, Wv (32-639)}.
__global__ __launch_bounds__(256)
void k1_misc(const float* __restrict__ x,   const float* __restrict__ Wq,
             const float* __restrict__ Wk,  const float* __restrict__ Wv,
             const float* __restrict__ Wfc, const float* __restrict__ Wo,
             const float* __restrict__ bo,  const float* __restrict__ bfc,
             __bf16* __restrict__ xh, __bf16* __restrict__ xl,
             __bf16* __restrict__ Ws, __bf16* __restrict__ Wch,
             __bf16* __restrict__ Wcl, float* __restrict__ bcomb) {
  __shared__ float sh[2 * 32 * 68];
  const int bx = blockIdx.x, tid = threadIdx.x;
  if (bx < 16) {
    float (*AsT)[68] = (float(*)[68])sh;
    float (*Bs)[68]  = (float(*)[68])(sh + 32 * 68);
    const int ty = tid >> 4, tx = tid & 15;
    const int m0 = (bx >> 2) * 64, n0 = (bx & 3) * 64;
    float acc[4][4] = {};
    for (int k0 = 0; k0 < 256; k0 += 32) {
#pragma unroll
      for (int jj = 0; jj < 2; ++jj) {
        int j = tid * 2 + jj;
        {
          int r = j >> 3, c4 = (j & 7) << 2;
          float4 av = *(const float4*)&Wfc[(size_t)(m0 + r) * 256 + k0 + c4];
          AsT[c4 + 0][r] = av.x; AsT[c4 + 1][r] = av.y;
          AsT[c4 + 2][r] = av.z; AsT[c4 + 3][r] = av.w;
        }
        {
          int r = j >> 4, c4 = (j & 15) << 2;
          *(float4*)&Bs[r][c4] = *(const float4*)&Wo[(size_t)(k0 + r) * 256 + n0 + c4];
        }
      }
      __syncthreads();
#pragma unroll
      for (int kk = 0; kk < 32; ++kk) {
        float4 a = *(const float4*)&AsT[kk][ty * 4];
        float4 b = *(const float4*)&Bs[kk][tx * 4];
        float av[4] = {a.x, a.y, a.z, a.w};
        float bv[4] = {b.x, b.y, b.z, b.w};
#pragma unroll
        for (int i = 0; i < 4; ++i)
#pragma unroll
          for (int j2 = 0; j2 < 4; ++j2)
            acc[i][j2] = fmaf(av[i], bv[j2], acc[i][j2]);
      }
      __syncthreads();
    }
#pragma unroll
    for (int i = 0; i < 4; ++i) {
      union { __bf16 h[4]; uint2 u; } ph, pl;
#pragma unroll
      for (int j = 0; j < 4; ++j) {
        __bf16 hb = (__bf16)acc[i][j];
        ph.h[j] = hb;
        pl.h[j] = (__bf16)(acc[i][j] - (float)hb);
      }
      size_t off = (size_t)(m0 + ty * 4 + i) * 256 + n0 + tx * 4;
      *(uint2*)(Wch + off) = ph.u;
      *(uint2*)(Wcl + off) = pl.u;
    }
  } else if (bx < 32) {
    float* red = sh;
    int r = tid >> 4, c = tid & 15;
    int row = (bx - 16) * 16 + r;
    float s = 0.0f;
    for (int k = c; k < 256; k += 16) s = fmaf(Wfc[(size_t)row * 256 + k], bo[k], s);
    red[tid] = s;
    __syncthreads();
    if (c == 0) {
      float t = 0.0f;
#pragma unroll
      for (int i = 0; i < 16; ++i) t += red[r * 16 + i];
      bcomb[row] = t + bfc[row];
    }
  } else {
    int g = (bx - 32) * 256 + tid;
    const float* src;
    __bf16 *dh, *dl;
    if (g < 131072) {
      src = x + (size_t)g * 8; dh = xh + (size_t)g * 8; dl = xl + (size_t)g * 8;
    } else {
      int e = g - 131072;
      int wsel = e >> 13;
      int inner = (e & 8191) * 8;
      src = (wsel == 0 ? Wq : (wsel == 1 ? Wk : Wv)) + inner;
      dh = Ws + wsel * 131072 + inner;
      dl = Ws + wsel * 131072 + 65536 + inner;
    }
    union { __bf16 h[8]; uint4 u; } ph, pl;
#pragma unroll
    for (int i = 0; i < 2; ++i) {
      float4 v = *(const float4*)(src + i * 4);
      float vv[4] = {v.x, v.y, v.z, v.w};
#pragma unroll
      for (int j = 0; j < 4; ++j) {
        __bf16 hb = (__bf16)vv[j];
        ph.h[i * 4 + j] = hb;
        pl.h[i * 4 + j] = (__bf16)(vv[j] - (float)hb);
      }
    }
    *(uint4*)dh = ph.u;
    *(uint4*)dl = pl.u;
  }
}

// ---------------------------------------------------------------------------
// Fused QKV projection + expmap prep + V^T/Vsum, split-bf16 MFMA.
// Grid (64, 12), 4 waves.
__global__ __launch_bounds__(256, 4)
void gemm_qkv_mfma(const __bf16* __restrict__ xh, const __bf16* __restrict__ xl,
                   const __bf16* __restrict__ Ws,
                   const float* __restrict__ bq, const float* __restrict__ bk,
                   const float* __restrict__ bv,
                   __bf16* __restrict__ Qbf, __bf16* __restrict__ Kbf,
                   __bf16* __restrict__ Vt, float* __restrict__ Vsum,
                   float4* __restrict__ qtab4, float4* __restrict__ ktab4,
                   float2* __restrict__ Kred) {
  __shared__ float4 kredsh[4];
  __shared__ __bf16 sh_vt[64][64];       // 8 KB (V path)
  __shared__ float  vsred[4][4][64];     // 4 KB (V path)
  const int tid = threadIdx.x, w = tid >> 6, lane = tid & 63;
  const int l15 = lane & 15, lg = lane >> 4;
  const int m0 = blockIdx.x * 64, nb = blockIdx.y;
  const int wsel = nb >> 2;
  const int n256b = (nb & 3) * 64;
  const __bf16* Wh = Ws + wsel * 131072;
  const __bf16* Wl = Wh + 65536;
  const int arow = m0 + w * 16 + l15;
  const __bf16* axh = xh + (size_t)arow * 256 + lg * 8;
  const __bf16* axl = xl + (size_t)arow * 256 + lg * 8;
  f32x4 acc0 = {0,0,0,0}, acc1 = {0,0,0,0}, acc2 = {0,0,0,0}, acc3 = {0,0,0,0};
#pragma unroll
  for (int k0 = 0; k0 < 256; k0 += 32) {
    bf16x8 ah = *(const bf16x8*)(axh + k0);
    bf16x8 al = *(const bf16x8*)(axl + k0);
#pragma unroll
    for (int g = 0; g < 4; ++g) {
      const size_t br = (size_t)(n256b + g * 16 + l15) * 256 + lg * 8 + k0;
      bf16x8 bh = *(const bf16x8*)(Wh + br);
      bf16x8 bl = *(const bf16x8*)(Wl + br);
      f32x4& acc = g == 0 ? acc0 : (g == 1 ? acc1 : (g == 2 ? acc2 : acc3));
      acc = __builtin_amdgcn_mfma_f32_16x16x32_bf16(ah, bh, acc, 0, 0, 0);
      acc = __builtin_amdgcn_mfma_f32_16x16x32_bf16(al, bh, acc, 0, 0, 0);
      acc = __builtin_amdgcn_mfma_f32_16x16x32_bf16(ah, bl, acc, 0, 0, 0);
    }
  }
  const float* bias = wsel == 0 ? bq : (wsel == 1 ? bk : bv);
  const int b = m0 >> 11;                    // block-uniform
  const int headA = n256b >> 5;              // {0,2,4,6}
  const int sLoc = m0 & 2047;                // t/s offset within the batch

  if (wsel == 2) {
    // ---- V: stage fp32+bias into LDS transpose + per-lane 4-t sums ----
#pragma unroll
    for (int g = 0; g < 4; ++g) {
      const f32x4& acc = g == 0 ? acc0 : (g == 1 ? acc1 : (g == 2 ? acc2 : acc3));
      int col = g * 16 + l15;
      float bval = bias[n256b + col];
      float p = 0.0f;
#pragma unroll
      for (int r = 0; r < 4; ++r) {
        float v = acc[r] + bval;
        sh_vt[col][w * 16 + lg * 4 + r] = (__bf16)v;
        p += v;
      }
      vsred[w][lg][col] = p;
    }
    __syncthreads();
    {   // coalesced V^T write: 256 threads x 32B (two uint4 each, 16 bf16)
      int col = tid >> 2, sg = tid & 3;
      int bh = (b << 3) + headA + (col >> 5);
      int d = col & 31;
      uint4 v0 = *(const uint4*)&sh_vt[col][sg * 16];
      uint4 v1 = *(const uint4*)&sh_vt[col][sg * 16 + 8];
      __bf16* dstp = Vt + ((size_t)bh * 32 + d) * 2048 + sLoc + sg * 16;
      *(uint4*)dstp = v0;
      *(uint4*)(dstp + 8) = v1;
    }
    if (tid < 128) {  // Vsum32: reduce 8 partials per (t32, col)
      int tgrp = tid >> 6, col = tid & 63;
      float s = 0.0f;
#pragma unroll
      for (int w2 = 0; w2 < 2; ++w2)
#pragma unroll
        for (int l2 = 0; l2 < 4; ++l2)
          s += vsred[tgrp * 2 + w2][l2][col];
      int bh = (b << 3) + headA + (col >> 5);
      int d = col & 31;
      Vsum[((size_t)bh * 64 + (sLoc >> 5) + tgrp) * 32 + d] = s;
    }
    return;
  }

  // ---- Q/K: fused expmap prep ----
  const float bv0 = bias[n256b + 0 * 16 + l15];
  const float bv1 = bias[n256b + 1 * 16 + l15];
  const float bv2 = bias[n256b + 2 * 16 + l15];
  const float bv3 = bias[n256b + 3 * 16 + l15];
  float ssA[4], ssB[4];
#pragma unroll
  for (int r = 0; r < 4; ++r) {
    acc0[r] += bv0; acc1[r] += bv1; acc2[r] += bv2; acc3[r] += bv3;
    ssA[r] = acc0[r] * acc0[r] + acc1[r] * acc1[r];
    ssB[r] = acc2[r] * acc2[r] + acc3[r] * acc3[r];
  }
#pragma unroll
  for (int mk = 1; mk < 16; mk <<= 1) {
#pragma unroll
    for (int r = 0; r < 4; ++r) {
      ssA[r] += __shfl_xor(ssA[r], mk);
      ssB[r] += __shfl_xor(ssB[r], mk);
    }
  }
  float scA[4], qqA[4], BvA[4], lgA[4];
  float scB[4], qqB[4], BvB[4], lgB_[4];
#pragma unroll
  for (int r = 0; r < 4; ++r) {
    {
      float ss = fmaxf(ssA[r], 1e-12f);
      float xv = sqrtf(ss);
      float ex = fast_exp2(-TWOLOG2E * xv);
      float opex = 1.0f + ex;
      float th = (1.0f - ex) / opex;
      scA[r] = th / xv;
      qqA[r] = th * th;
      BvA[r] = 4.0f * ex / (opex * opex);
      lgA[r] = 2.0f - TWOLOG2E * xv - 2.0f * fast_log2(opex);
    }
    {
      float ss = fmaxf(ssB[r], 1e-12f);
      float xv = sqrtf(ss);
      float ex = fast_exp2(-TWOLOG2E * xv);
      float opex = 1.0f + ex;
      float th = (1.0f - ex) / opex;
      scB[r] = th / xv;
      qqB[r] = th * th;
      BvB[r] = 4.0f * ex / (opex * opex);
      lgB_[r] = 2.0f - TWOLOG2E * xv - 2.0f * fast_log2(opex);
    }
  }
  __bf16* dst = wsel == 0 ? Qbf : Kbf;
  float4* tab = wsel == 0 ? qtab4 : ktab4;
  const int headB = headA + 1;
  const int bhA = (b << 3) + headA, bhB = (b << 3) + headB;
  const int sbase = sLoc + w * 16 + lg * 4;
#pragma unroll
  for (int r = 0; r < 4; ++r) {
    int s = sbase + r;
    size_t baseA = ((size_t)bhA * 2048 + s) * 32;
    size_t baseB = ((size_t)bhB * 2048 + s) * 32;
    dst[baseA + l15]      = (__bf16)(acc0[r] * scA[r]);
    dst[baseA + 16 + l15] = (__bf16)(acc1[r] * scA[r]);
    dst[baseB + l15]      = (__bf16)(acc2[r] * scB[r]);
    dst[baseB + 16 + l15] = (__bf16)(acc3[r] * scB[r]);
    if (l15 == 0) {
      if (wsel == 0) {
        tab[(size_t)bhA * 2048 + s] = float4{qqA[r], ALPHA * lgA[r], BvA[r], 0.0f};
        tab[(size_t)bhB * 2048 + s] = float4{qqB[r], ALPHA * lgB_[r], BvB[r], 0.0f};
      } else {
        tab[(size_t)bhA * 2048 + s] = float4{qqA[r], BvA[r], ALPHA * lgA[r], 0.0f};
        tab[(size_t)bhB * 2048 + s] = float4{qqB[r], BvB[r], ALPHA * lgB_[r], 0.0f};
      }
    }
  }
  if (wsel == 1) {
    float mnA = fminf(fminf(qqA[0], qqA[1]), fminf(qqA[2], qqA[3]));
    float mxA = fmaxf(fmaxf(BvA[0], BvA[1]), fmaxf(BvA[2], BvA[3]));
    float mnB = fminf(fminf(qqB[0], qqB[1]), fminf(qqB[2], qqB[3]));
    float mxB = fmaxf(fmaxf(BvB[0], BvB[1]), fmaxf(BvB[2], BvB[3]));
    mnA = fminf(mnA, __shfl_xor(mnA, 16)); mnA = fminf(mnA, __shfl_xor(mnA, 32));
    mxA = fmaxf(mxA, __shfl_xor(mxA, 16)); mxA = fmaxf(mxA, __shfl_xor(mxA, 32));
    mnB = fminf(mnB, __shfl_xor(mnB, 16)); mnB = fminf(mnB, __shfl_xor(mnB, 32));
    mxB = fmaxf(mxB, __shfl_xor(mxB, 16)); mxB = fmaxf(mxB, __shfl_xor(mxB, 32));
    if (lane == 0) kredsh[w] = float4{mnA, mxA, mnB, mxB};
    __syncthreads();
    if (tid == 0) {
      float4 a = kredsh[0], b4 = kredsh[1], c4 = kredsh[2], d4 = kredsh[3];
      float MnA = fminf(fminf(a.x, b4.x), fminf(c4.x, d4.x));
      float MxA = fmaxf(fmaxf(a.y, b4.y), fmaxf(c4.y, d4.y));
      float MnB = fminf(fminf(a.z, b4.z), fminf(c4.z, d4.z));
      float MxB = fmaxf(fmaxf(a.w, b4.w), fmaxf(c4.w, d4.w));
      int bx31 = blockIdx.x & 31;
      Kred[bhA * 32 + bx31] = float2{MnA, MxA};
      Kred[bhB * 32 + bx31] = float2{MnB, MxB};
    }
  }
}

// ---------------------------------------------------------------------------
// Flash attention (round-16 body) with XCD-aware block swizzle.
// 1-D grid of 2048; wgid&7 = bh low bits so each bh's 128 blocks share an XCD.
__global__ __launch_bounds__(256, 4)
void attn_mfma(const __bf16* __restrict__ Qbf, const __bf16* __restrict__ Kbf,
               const __bf16* __restrict__ Vt,  const float4* __restrict__ qtab4,
               const float4* __restrict__ ktab4, const float* __restrict__ Vsum,
               const float2* __restrict__ Kred,
               __bf16* __restrict__ PNb, float* __restrict__ PD) {
  __shared__ __bf16 Pt[4][16][72];   // rare-path per-wave P^T (wave-private)
  const int tid = threadIdx.x;
  const int wid = tid >> 6, lane = tid & 63;
  const int l15 = lane & 15, lg = lane >> 4;
  // XCD-aware decode: bh low 3 bits = wgid % 8 (XCD id under round-robin).
  const int wgid = blockIdx.x;
  const int rest = wgid >> 3;              // 0..255
  const int sblk = rest & 31;
  const int t2   = rest >> 5;              // 0..7
  const int tc   = t2 & 3;
  const int bh   = ((t2 >> 2) << 3) | (wgid & 7);
  const int s0 = sblk * 64 + wid * 16;

  bf16x8 qfrag = *(const bf16x8*)(Qbf + ((size_t)bh * 2048 + s0 + l15) * 32 + lg * 8);
  float4 qt = qtab4[bh * 2048 + s0 + l15];
  const float qq = qt.x, Bq = qt.z;
  const float eminRow = EMIN - qt.y;
  const float wclipf = (float)(__bf16)fast_exp2(eminRow);   // bf16-quantized
  float wrow[4];
#pragma unroll
  for (int r = 0; r < 4; ++r)
    wrow[r] = (float)(__bf16)fast_exp2(EMIN - qtab4[bh * 2048 + s0 + lg * 4 + r].y);

  float kkmin = 1.0f, bkmax = 0.0f;
#pragma unroll
  for (int j = 0; j < 32; ++j) {
    float2 kr = Kred[bh * 32 + j];
    kkmin = fminf(kkmin, kr.x);
    bkmax = fmaxf(bkmax, kr.y);
  }
  const float thr_all = fmaf(0.5f * qq, kkmin,
                             fmaf(Bq * NEG_INV_2CHI, bkmax, 0.5f));

  const __bf16* Kbase = Kbf + ((size_t)bh << 16);
  const __bf16* Vbase = Vt + ((size_t)bh << 16);
  const float4* Tk = ktab4 + bh * 2048;
  const float*  VsBase = Vsum + (size_t)bh * 64 * 32;
  __bf16* Pw = &Pt[wid][0][0];

  f32x4 accO0 = {0.f, 0.f, 0.f, 0.f};
  f32x4 accO1 = {0.f, 0.f, 0.f, 0.f};
  float den = 0.0f;
  int nclip = 0;
  const f32x4 zero = {0.f, 0.f, 0.f, 0.f};
  const int tbeg = tc * 512;
  const int stag = sblk & 7;

  bf16x8 kfA0, kfA1, kfA2, kfA3, kfB0, kfB1, kfB2, kfB3;
  float vA0, vA1, vA2, vA3, vB0, vB1, vB2, vB3;

#define LOAD_SET(K0, K1, K2, K3, V0, V1, V2, V3, T0)                          \
  {                                                                           \
    const int _t = (T0);                                                      \
    K0 = *(const bf16x8*)(Kbase + (size_t)(_t + 0 * 16 + l15) * 32 + lg * 8); \
    K1 = *(const bf16x8*)(Kbase + (size_t)(_t + 1 * 16 + l15) * 32 + lg * 8); \
    K2 = *(const bf16x8*)(Kbase + (size_t)(_t + 2 * 16 + l15) * 32 + lg * 8); \
    K3 = *(const bf16x8*)(Kbase + (size_t)(_t + 3 * 16 + l15) * 32 + lg * 8); \
    const int _ti = _t >> 5;                                                  \
    V0 = VsBase[_ti * 32 + l15];                                              \
    V1 = VsBase[(_ti + 1) * 32 + l15];                                        \
    V2 = VsBase[_ti * 32 + 16 + l15];                                         \
    V3 = VsBase[(_ti + 1) * 32 + 16 + l15];                                   \
  }

#define COMPUTE_SET(K0, K1, K2, K3, V0, V1, V2, V3, T0)                       \
  {                                                                           \
    const int _t0 = (T0);                                                     \
    __builtin_amdgcn_s_setprio(1);                                            \
    _Pragma("unroll")                                                         \
    for (int h = 0; h < 2; ++h) {                                             \
      f32x4 S[2];                                                             \
      bool ok = true;                                                         \
      _Pragma("unroll")                                                       \
      for (int s2 = 0; s2 < 2; ++s2) {                                        \
        bf16x8 kf = (h == 0) ? (s2 == 0 ? K0 : K1) : (s2 == 0 ? K2 : K3);     \
        f32x4 Sv = __builtin_amdgcn_mfma_f32_16x16x32_bf16(kf, qfrag, zero,   \
                                                           0, 0, 0);          \
        S[s2] = Sv;                                                           \
        float m = fmaxf(fmaxf(Sv[0], Sv[1]), fmaxf(Sv[2], Sv[3]));            \
        ok &= (m <= thr_all);                                                 \
      }                                                                       \
      if (__all((int)ok)) {                                                   \
        ++nclip;                                                              \
        const float vsA = h ? V1 : V0;                                        \
        const float vsB = h ? V3 : V2;                                        \
        _Pragma("unroll")                                                     \
        for (int r = 0; r < 4; ++r) {                                         \
          accO0[r] = fmaf(wrow[r], vsA, accO0[r]);                            \
          accO1[r] = fmaf(wrow[r], vsB, accO1[r]);                            \
        }                                                                     \
      } else {                                                                \
        _Pragma("unroll")                                                     \
        for (int s2 = 0; s2 < 2; ++s2) {                                      \
          const int sub = h * 2 + s2;                                         \
          const int tk = _t0 + sub * 16 + lg * 4;                             \
          f32x4 Sv = S[s2];                                                   \
          float w[4];                                                         \
          _Pragma("unroll")                                                   \
          for (int r = 0; r < 4; ++r) {                                       \
            float4 T = Tk[tk + r];                                            \
            float qk2 = Sv[r] + Sv[r];                                        \
            float u = (qq + T.x) - qk2;                                       \
            float d = fmaf(qq, T.x, 1.0f) - qk2;                              \
            float p = fmaxf(u * d, 0.0f);                                     \
            float sq = sqrtf(p);                                              \
            float m2 = fmaf(2.0f, sq, u + d);                                 \
            float e = fmaf(-ALPHA, fast_log2(m2), T.z);                       \
            e = fmaxf(e, eminRow);                                            \
            w[r] = fast_exp2(e);                                              \
          }                                                                   \
          den += (w[0] + w[1]) + (w[2] + w[3]);                               \
          union { __bf16 hh[4]; uint2 u2; } pk;                               \
          pk.hh[0] = (__bf16)w[0]; pk.hh[1] = (__bf16)w[1];                   \
          pk.hh[2] = (__bf16)w[2]; pk.hh[3] = (__bf16)w[3];                   \
          *(uint2*)&Pw[l15 * 72 + sub * 16 + lg * 4] = pk.u2;                 \
        }                                                                     \
        bf16x8 pfrag = *(const bf16x8*)&Pw[l15 * 72 + h * 32 + lg * 8];       \
        bf16x8 v0 = *(const bf16x8*)(Vbase + (size_t)l15 * 2048 + _t0 +       \
                                     h * 32 + lg * 8);                        \
        bf16x8 v1 = *(const bf16x8*)(Vbase + (size_t)(16 + l15) * 2048 +      \
                                     _t0 + h * 32 + lg * 8);                  \
        accO0 = __builtin_amdgcn_mfma_f32_16x16x32_bf16(pfrag, v0, accO0,     \
                                                        0, 0, 0);             \
        accO1 = __builtin_amdgcn_mfma_f32_16x16x32_bf16(pfrag, v1, accO1,     \
                                                        0, 0, 0);             \
      }                                                                       \
    }                                                                         \
    __builtin_amdgcn_s_setprio(0);                                            \
  }

  LOAD_SET(kfA0, kfA1, kfA2, kfA3, vA0, vA1, vA2, vA3,
           tbeg + ((stag & 7) << 6));

#pragma unroll
  for (int i = 0; i < 8; ++i) {
    const int tcur = tbeg + (((i + stag) & 7) << 6);
    const int tnxt = tbeg + (((i + 1 + stag) & 7) << 6);
    if ((i & 1) == 0) {
      if (i < 7) LOAD_SET(kfB0, kfB1, kfB2, kfB3, vB0, vB1, vB2, vB3, tnxt);
      COMPUTE_SET(kfA0, kfA1, kfA2, kfA3, vA0, vA1, vA2, vA3, tcur);
    } else {
      if (i < 7) LOAD_SET(kfA0, kfA1, kfA2, kfA3, vA0, vA1, vA2, vA3, tnxt);
      COMPUTE_SET(kfB0, kfB1, kfB2, kfB3, vB0, vB1, vB2, vB3, tcur);
    }
  }
#undef LOAD_SET
#undef COMPUTE_SET

  den = fmaf(8.0f * wclipf, (float)nclip, den);
  den += __shfl_xor(den, 16);
  den += __shfl_xor(den, 32);
  size_t pbase = ((size_t)tc * 16 + bh) * 2048;
  if (lg == 0) PD[pbase + s0 + l15] = den;
#pragma unroll
  for (int r = 0; r < 4; ++r) {
    int sl = lg * 4 + r;
    size_t row = (pbase + s0 + sl) * 32;
    PNb[row + l15]      = (__bf16)accO0[r];
    PNb[row + 16 + l15] = (__bf16)accO1[r];
  }
}

// ---------------------------------------------------------------------------
// Sum the 4 t-chunk bf16 partials, normalize, write AO as bf16 (h, l) pair.
__global__ __launch_bounds__(256)
void combine4(const __bf16* __restrict__ PNb, const float* __restrict__ PD,
              __bf16* __restrict__ AOh, __bf16* __restrict__ AOl) {
  int idx = blockIdx.x * 256 + threadIdx.x;   // 0..32767 = (bh, s)
  int bh = idx >> 11, s = idx & 2047;
  int b = bh >> 3, h = bh & 7;
  float den = 0.0f;
#pragma unroll
  for (int c = 0; c < 4; ++c) den += PD[((size_t)c * 16 + bh) * 2048 + s];
  float r = 1.0f / den;
  size_t ob = ((size_t)b * 2048 + s) * 256 + h * 32;
#pragma unroll
  for (int i = 0; i < 4; ++i) {               // 8 dh per iter
    float acc8[8] = {};
#pragma unroll
    for (int c = 0; c < 4; ++c) {
      bf16x8 v = *(const bf16x8*)&PNb[((((size_t)c * 16 + bh) * 2048 + s) * 32) + i * 8];
#pragma unroll
      for (int j = 0; j < 8; ++j) acc8[j] += (float)v[j];
    }
    union { __bf16 h8[8]; uint4 u; } ph, pl;
#pragma unroll
    for (int j = 0; j < 8; ++j) {
      float val = acc8[j] * r;
      __bf16 hb = (__bf16)val;
      ph.h8[j] = hb;
      pl.h8[j] = (__bf16)(val - (float)hb);
    }
    *(uint4*)(AOh + ob + i * 8) = ph.u;
    *(uint4*)(AOl + ob + i * 8) = pl.u;
  }
}

// ---------------------------------------------------------------------------
// Output projection, split-bf16 MFMA: out = AO @ Wcomb^T + bcomb. Grid (64,4).
__global__ __launch_bounds__(256, 1)
void gemm_out_mfma(const __bf16* __restrict__ aoh, const __bf16* __restrict__ aol,
                   const __bf16* __restrict__ Wch, const __bf16* __restrict__ Wcl,
                   const float* __restrict__ bcomb, float* __restrict__ out) {
  const int tid = threadIdx.x, w = tid >> 6, lane = tid & 63;
  const int l15 = lane & 15, lg = lane >> 4;
  const int m0 = blockIdx.x * 64, n0 = blockIdx.y * 64;
  const int arow = m0 + w * 16 + l15;
  const __bf16* axh = aoh + (size_t)arow * 256 + lg * 8;
  const __bf16* axl = aol + (size_t)arow * 256 + lg * 8;
  f32x4 acc0 = {0,0,0,0}, acc1 = {0,0,0,0}, acc2 = {0,0,0,0}, acc3 = {0,0,0,0};
#pragma unroll
  for (int k0 = 0; k0 < 256; k0 += 32) {
    bf16x8 ah = *(const bf16x8*)(axh + k0);
    bf16x8 al = *(const bf16x8*)(axl + k0);
#pragma unroll
    for (int g = 0; g < 4; ++g) {
      const size_t br = (size_t)(n0 + g * 16 + l15) * 256 + lg * 8 + k0;
      bf16x8 bh = *(const bf16x8*)(Wch + br);
      bf16x8 bl = *(const bf16x8*)(Wcl + br);
      f32x4& acc = g == 0 ? acc0 : (g == 1 ? acc1 : (g == 2 ? acc2 : acc3));
      acc = __builtin_amdgcn_mfma_f32_16x16x32_bf16(ah, bh, acc, 0, 0, 0);
      acc = __builtin_amdgcn_mfma_f32_16x16x32_bf16(al, bh, acc, 0, 0, 0);
      acc = __builtin_amdgcn_mfma_f32_16x16x32_bf16(ah, bl, acc, 0, 0, 0);
    }
  }
#pragma unroll
  for (int g = 0; g < 4; ++g) {
    const f32x4& acc = g == 0 ? acc0 : (g == 1 ? acc1 : (g == 2 ? acc2 : acc3));
    int n = n0 + g * 16 + l15;
    float bval = bcomb[n];
#pragma unroll
    for (int r = 0; r < 4; ++r) {
      int m = m0 + w * 16 + lg * 4 + r;
      out[(size_t)m * 256 + n] = acc[r] + bval;
    }
  }
}

// ---------------------------------------------------------------------------
extern "C" void kernel_launch(void* const* d_in, const int* in_sizes, int n_in,
                              void* d_out, int out_size, void* d_ws, size_t ws_size,
                              hipStream_t stream) {
  const float* x   = (const float*)d_in[0];
  const float* Wq  = (const float*)d_in[1];
  const float* bq  = (const float*)d_in[2];
  const float* Wk  = (const float*)d_in[3];
  const float* bk  = (const float*)d_in[4];
  const float* Wv  = (const float*)d_in[5];
  const float* bv  = (const float*)d_in[6];
  const float* Wo  = (const float*)d_in[7];
  const float* bo  = (const float*)d_in[8];
  const float* Wfc = (const float*)d_in[9];
  const float* bfc = (const float*)d_in[10];

  float* ws = (float*)d_ws;
  // Workspace layout (float offsets); ~42.5 MB total.
  __bf16* Qbf = (__bf16*)(ws + (3 << 20));              // 1M bf16
  __bf16* Kbf = (__bf16*)(ws + (3 << 20) + (1 << 19));  // 1M bf16
  __bf16* Vtb = (__bf16*)(ws + (4 << 20));              // 1M bf16
  float4* qtab4 = (float4*)(ws + (4 << 20) + (1 << 19));             // 128K f
  float4* ktab4 = (float4*)(ws + (4 << 20) + (1 << 19) + (1 << 17)); // 128K f
  float*  Vsum  = ws + (4 << 20) + (1 << 19) + (2 << 17);            // 32K f
  __bf16* Wch   = (__bf16*)(Vsum + (1 << 15));          // 64K bf16 (32K f)
  __bf16* Wcl   = Wch + 65536;                          // 64K bf16
  float*  bcomb = Vsum + (1 << 15) + (1 << 16);         // 256
  float2* Kred  = (float2*)(bcomb + 256);               // 512 float2 (1K f)
  __bf16* xh = (__bf16*)(ws + (5 << 20));               // 1M bf16
  __bf16* xl = (__bf16*)(ws + (5 << 20) + (1 << 19));   // 1M bf16
  __bf16* Wsplit = (__bf16*)(ws + (6 << 20));           // 393216 bf16
  __bf16* PNb = (__bf16*)(ws + (6 << 20) + (1 << 18));  // 4M bf16 (2M f)
  float* PD = ws + (6 << 20) + (1 << 18) + (2 << 20);   // 128K
  __bf16* AOh = (__bf16*)ws;                            // reuse slab 0
  __bf16* AOl = (__bf16*)(ws + (1 << 19));              // reuse slab 0

  dim3 blk(256);
  k1_misc<<<dim3(640), blk, 0, stream>>>(x, Wq, Wk, Wv, Wfc, Wo, bo, bfc,
                                         xh, xl, Wsplit, Wch, Wcl, bcomb);
  gemm_qkv_mfma<<<dim3(64, 12), blk, 0, stream>>>(xh, xl, Wsplit, bq, bk, bv,
                                                  Qbf, Kbf, Vtb, Vsum,
                                                  qtab4, ktab4, Kred);
  attn_mfma<<<dim3(2048), blk, 0, stream>>>(Qbf, Kbf, Vtb, qtab4, ktab4,
                                            Vsum, Kred, PNb, PD);
  combine4<<<dim3(128), blk, 0, stream>>>(PNb, PD, AOh, AOl);
  gemm_out_mfma<<<dim3(64, 4), blk, 0, stream>>>(AOh, AOl, Wch, Wcl, bcomb,
                                                 (float*)d_out);
}